// Round 1
// baseline (1135.294 us; speedup 1.0000x reference)
//
#include <hip/hip_runtime.h>
#include <math.h>

#define GG 4096
#define PP 4096
#define HH 64
#define BB 4
#define E1N 81920
#define E2N 81920
#define FFD 512
#define BNEPS 1e-5f

// ---------------- workspace layout (float offsets) ----------------
#define OF_STATS   0          // 6 slots x 256 (mean[128] + invstd[128])
#define OF_DEGCO   2048
#define OF_DEGGO   6144
#define OF_PSLOT   10240      // 8 x 64
#define OF_ETOT    10752      // 4 x 64
#define OF_HDC     11008      // 4 x 32
#define OF_HE      11136      // 4 x 32
#define OF_AGGCO   12288      // 4096 x 64
#define OF_BASEIN  274432     // 4096 x 64
#define OF_Y1      536576     // 4096 x 64
#define OF_Y2      798720     // 4096 x 64
#define OF_FLAT    1060864    // 16384 x 64
#define OF_RW1     2109440    // 16384 x 128
#define OF_RW2     4206592    // 16384 x 64
#define OF_OUT     5255168    // 16384 x 64
#define OF_QKV     6303744    // 16384 x 192
#define OF_CTX     9449472    // 16384 x 64
#define OF_H1      10498048   // 16384 x 64
#define OF_FFT     OF_FLAT    // 16384 x 512 (aliases FLAT..QKV, all dead by then)
#define OF_FFO     OF_CTX     // 16384 x 64  (aliases CTX, dead by then)

// ---------------- simple utility kernels ----------------
__global__ void k_fill(float* p, float v, int n) {
    int i = blockIdx.x * 256 + threadIdx.x;
    if (i < n) p[i] = v;
}

__global__ void k_edge_deg(const int* __restrict__ ei, const float* __restrict__ w,
                           float* deg, int E) {
    int e = blockIdx.x * 256 + threadIdx.x;
    if (e < E) atomicAdd(&deg[ei[E + e]], w[e]);
}

__global__ void k_rsqrt_ip(float* p, int n) {
    int i = blockIdx.x * 256 + threadIdx.x;
    if (i < n) p[i] = rsqrtf(p[i]);
}

// agg[i][h] = x[i][h] * dinv[i]^2   (self-loop term, weight 1)
__global__ void k_agg_init(const float* __restrict__ x, const float* __restrict__ dinv,
                           float* agg, int n) {
    int i = blockIdx.x * 256 + threadIdx.x;
    if (i < n * HH) {
        int node = i >> 6;
        float di = dinv[node];
        agg[i] = x[i] * di * di;
    }
}

// one wave (64 lanes = 64 h) per edge
__global__ void k_edge_agg(const int* __restrict__ ei, const float* __restrict__ w,
                           const float* __restrict__ dinv, const float* __restrict__ x,
                           float* agg, int E) {
    int gid = blockIdx.x * 256 + threadIdx.x;
    int e = gid >> 6, h = gid & 63;
    if (e < E) {
        int src = ei[e], dst = ei[E + e];
        float norm = dinv[dst] * w[e] * dinv[src];
        atomicAdd(&agg[dst * HH + h], norm * x[src * HH + h]);
    }
}

// column mean/invstd over N rows (block per column)
__global__ void k_colstats(const float* __restrict__ X, int N, int C,
                           float* mean, float* invstd) {
    int c = blockIdx.x;
    float s = 0.f, sq = 0.f;
    for (int r = threadIdx.x; r < N; r += 256) {
        float v = X[r * C + c];
        s += v; sq += v * v;
    }
    __shared__ float ls[256], lq[256];
    ls[threadIdx.x] = s; lq[threadIdx.x] = sq;
    __syncthreads();
    for (int o = 128; o > 0; o >>= 1) {
        if (threadIdx.x < o) { ls[threadIdx.x] += ls[threadIdx.x + o]; lq[threadIdx.x] += lq[threadIdx.x + o]; }
        __syncthreads();
    }
    if (threadIdx.x == 0) {
        float m = ls[0] / (float)N;
        float v = lq[0] / (float)N - m * m;
        mean[c] = m;
        invstd[c] = rsqrtf(v + BNEPS);
    }
}

// base_in = relu(bn(gene_emb)) + 0.2*(agg @ Wco^T + bco)    (4 rows / block)
__global__ void k_base_combine(const float* __restrict__ gene_emb, const float* __restrict__ agg,
                               const float* __restrict__ W, const float* __restrict__ bias,
                               const float* __restrict__ m, const float* __restrict__ is,
                               const float* __restrict__ bg, const float* __restrict__ bb,
                               float* out) {
    __shared__ float Wt[64][65];
    __shared__ float a[4][64];
    int t = threadIdx.x;
    for (int i = t; i < 4096; i += 256) Wt[i & 63][i >> 6] = W[i];
    int rr = t >> 6, h = t & 63;
    int g = blockIdx.x * 4 + rr;
    a[rr][h] = agg[g * 64 + h];
    __syncthreads();
    float y = bias[h];
    const float* ar = a[rr];
    #pragma unroll 8
    for (int k = 0; k < 64; k++) y += ar[k] * Wt[k][h];
    float v = gene_emb[g * 64 + h];
    v = (v - m[h]) * is[h] * bg[h] + bb[h];
    v = fmaxf(v, 0.f);
    out[g * 64 + h] = v + 0.2f * y;
}

// generic GEMM: Y[N,Cout] = f(X[N,Cin]) @ W[Cout,Cin]^T + bias
// f = optional BN (batch-stat, per input column) then optional ReLU
__launch_bounds__(256)
__global__ void k_gemm(const float* __restrict__ X, const float* __restrict__ W,
                       const float* __restrict__ bias, float* __restrict__ Y,
                       int N, int Cin, int Cout,
                       const float* __restrict__ bnm, const float* __restrict__ bni,
                       const float* __restrict__ bng, const float* __restrict__ bnb,
                       int relu_in) {
    __shared__ float Xs[32][129];
    __shared__ float Wt[128][65];
    int row0 = blockIdx.x * 32;
    int c0 = threadIdx.x & 63, rg = threadIdx.x >> 6;
    for (int cb = 0; cb < Cout; cb += 64) {
        float acc[8];
        #pragma unroll
        for (int j = 0; j < 8; j++) acc[j] = 0.f;
        for (int k0 = 0; k0 < Cin; k0 += 128) {
            int kc = (Cin - k0 < 128) ? (Cin - k0) : 128;
            __syncthreads();
            // stage X (with input transform)
            for (int i = threadIdx.x; i < 32 * kc; i += 256) {
                int r, k;
                if (kc == 128) { r = i >> 7; k = i & 127; } else { r = i >> 6; k = i & 63; }
                float v = X[(row0 + r) * Cin + k0 + k];
                if (bnm) {
                    int c = k0 + k;
                    v = (v - bnm[c]) * bni[c] * bng[c] + bnb[c];
                }
                if (relu_in) v = fmaxf(v, 0.f);
                Xs[r][k] = v;
            }
            // stage W transposed
            for (int i = threadIdx.x; i < 64 * kc; i += 256) {
                int co, k;
                if (kc == 128) { co = i >> 7; k = i & 127; } else { co = i >> 6; k = i & 63; }
                Wt[k][co] = W[(cb + co) * Cin + k0 + k];
            }
            __syncthreads();
            #pragma unroll 4
            for (int k = 0; k < kc; k++) {
                float w = Wt[k][c0];
                #pragma unroll
                for (int j = 0; j < 8; j++) acc[j] += Xs[rg * 8 + j][k] * w;
            }
        }
        float bi = bias[cb + c0];
        #pragma unroll
        for (int j = 0; j < 8; j++)
            Y[(row0 + rg * 8 + j) * Cout + cb + c0] = acc[j] + bi;
    }
}

// plain BN apply (no relu), C=64
__global__ void k_bn_apply(const float* __restrict__ X, float* Y, int total,
                           const float* __restrict__ m, const float* __restrict__ is,
                           const float* __restrict__ g, const float* __restrict__ b) {
    int i = blockIdx.x * 256 + threadIdx.x;
    if (i < total) {
        int c = i & 63;
        Y[i] = (X[i] - m[c]) * is[c] * g[c] + b[c];
    }
}

// flat_pre[b,g,h] = bn(y2)[g,h] + etot[b,h]
__global__ void k_flatpre(const float* __restrict__ y2, const float* __restrict__ etot,
                          const float* __restrict__ m, const float* __restrict__ is,
                          const float* __restrict__ g2, const float* __restrict__ b2,
                          float* out) {
    int i = blockIdx.x * 256 + threadIdx.x;   // over B*G*64
    int h = i & 63;
    int b = i >> 18;                           // G*H = 2^18
    int gh = i & (GG * HH - 1);
    float v = y2[gh];
    v = (v - m[h]) * is[h] * g2[h] + b2[h];
    out[i] = v + etot[b * 64 + h];
}

// pert slot init: self-loop term of SGConv for the 8 gathered nodes
__global__ void k_pert_slots(const int* __restrict__ pidx, const float* __restrict__ tbl,
                             const float* __restrict__ dinv, float* pslot) {
    int i = threadIdx.x;   // 512
    int s = i >> 6, h = i & 63;
    int n = pidx[s];
    float di = dinv[n];
    pslot[i] = tbl[n * 64 + h] * di * di;
}

// scan GO edges; accumulate into the 8 gathered rows
__global__ void k_pert_edges(const int* __restrict__ pidx, const int* __restrict__ ei,
                             const float* __restrict__ w, const float* __restrict__ dinv,
                             const float* __restrict__ tbl, float* pslot) {
    int e = blockIdx.x * 256 + threadIdx.x;
    if (e >= E2N) return;
    int dst = ei[E2N + e];
    int src = ei[e];
    for (int s = 0; s < 8; s++) {
        if (pidx[s] == dst) {
            float norm = dinv[dst] * w[e] * dinv[src];
            for (int h = 0; h < 64; h++)
                atomicAdd(&pslot[s * 64 + h], norm * tbl[src * 64 + h]);
        }
    }
}

// single block: pge rows -> psum -> pf MLP (BN over B=4 rows) -> etot
__global__ void k_pert_mlp(const float* __restrict__ pslot,
                           const float* __restrict__ gw, const float* __restrict__ gb,
                           const float* __restrict__ w1, const float* __restrict__ b1,
                           const float* __restrict__ g1, const float* __restrict__ be1,
                           const float* __restrict__ w2, const float* __restrict__ b2,
                           const float* __restrict__ g2, const float* __restrict__ be2,
                           float* etot) {
    __shared__ float pge[8][64], psum[4][64], y[4][64], mh[64], ih[64];
    int t = threadIdx.x;
    for (int j = t; j < 512; j += 256) {
        int s = j >> 6, h = j & 63;
        float acc = gb[h];
        for (int k = 0; k < 64; k++) acc += pslot[s * 64 + k] * gw[h * 64 + k];
        pge[s][h] = acc;
    }
    __syncthreads();
    { int b = t >> 6, h = t & 63; psum[b][h] = pge[2 * b][h] + pge[2 * b + 1][h]; }
    __syncthreads();
    { int b = t >> 6, h = t & 63;
      float acc = b1[h];
      for (int k = 0; k < 64; k++) acc += psum[b][k] * w1[h * 64 + k];
      y[b][h] = acc; }
    __syncthreads();
    if (t < 64) {
        float s = 0.f, sq = 0.f;
        for (int b = 0; b < 4; b++) { float v = y[b][t]; s += v; sq += v * v; }
        float m = s * 0.25f;
        mh[t] = m; ih[t] = rsqrtf(sq * 0.25f - m * m + BNEPS);
    }
    __syncthreads();
    { int b = t >> 6, h = t & 63;
      float v = (y[b][h] - mh[h]) * ih[h] * g1[h] + be1[h];
      psum[b][h] = fmaxf(v, 0.f); }
    __syncthreads();
    { int b = t >> 6, h = t & 63;
      float acc = b2[h];
      for (int k = 0; k < 64; k++) acc += psum[b][k] * w2[h * 64 + k];
      y[b][h] = acc; }
    __syncthreads();
    if (t < 64) {
        float s = 0.f, sq = 0.f;
        for (int b = 0; b < 4; b++) { float v = y[b][t]; s += v; sq += v * v; }
        float m = s * 0.25f;
        mh[t] = m; ih[t] = rsqrtf(sq * 0.25f - m * m + BNEPS);
    }
    __syncthreads();
    { int b = t >> 6, h = t & 63;
      etot[b * 64 + h] = (y[b][h] - mh[h]) * ih[h] * g2[h] + be2[h]; }
}

// flash attention, fp32. grid (G/64, B*NH). block 256.
__launch_bounds__(256)
__global__ void k_attn(const float* __restrict__ qkv, const float* __restrict__ mask,
                       float* __restrict__ ctx) {
    const int bh = blockIdx.y;
    const int b = bh >> 1, h = bh & 1;
    const int q0 = blockIdx.x * 64;
    const int t = threadIdx.x;
    __shared__ float Qs[64][33];
    __shared__ float Ks[64][33];
    __shared__ float Vs[64][32];
    __shared__ float Ps[64][67];
    __shared__ float red[64][17];
    __shared__ float m_sh[64], l_sh[64], al_sh[64];

    for (int i = t; i < 2048; i += 256) {
        int r = i >> 5, d = i & 31;
        Qs[r][d] = qkv[((size_t)b * GG + (q0 + r)) * 192 + h * 32 + d];
    }
    if (t < 64) { m_sh[t] = -1e30f; l_sh[t] = 0.f; }

    const int qg = t >> 4;           // 0..15
    const int kg = t & 15;           // 0..15
    const int lane = t & 63;
    const int wv = t >> 6;           // 0..3
    const int qi0 = (lane >> 2) * 4; // PV row base
    const int dg0 = (lane & 3) * 8;  // PV d base
    float oacc[4][8];
    #pragma unroll
    for (int j = 0; j < 4; j++)
        #pragma unroll
        for (int m2 = 0; m2 < 8; m2++) oacc[j][m2] = 0.f;
    const float scale = 0.17677669529663687f; // 1/sqrt(32)

    for (int k0 = 0; k0 < GG; k0 += 64) {
        __syncthreads();
        for (int i = t; i < 2048; i += 256) {
            int r = i >> 5, d = i & 31;
            size_t base = ((size_t)b * GG + (k0 + r)) * 192 + h * 32 + d;
            Ks[r][d] = qkv[base + 64];
            Vs[r][d] = qkv[base + 128];
        }
        __syncthreads();
        // scores: 4q x 4k per thread
        float s[4][4];
        #pragma unroll
        for (int j = 0; j < 4; j++)
            #pragma unroll
            for (int i2 = 0; i2 < 4; i2++) s[j][i2] = 0.f;
        for (int d = 0; d < 32; d++) {
            float qv[4], kv[4];
            #pragma unroll
            for (int j = 0; j < 4; j++) qv[j] = Qs[qg * 4 + j][d];
            #pragma unroll
            for (int i2 = 0; i2 < 4; i2++) kv[i2] = Ks[kg + 16 * i2][d];
            #pragma unroll
            for (int j = 0; j < 4; j++)
                #pragma unroll
                for (int i2 = 0; i2 < 4; i2++) s[j][i2] += qv[j] * kv[i2];
        }
        #pragma unroll
        for (int j = 0; j < 4; j++) {
            float pm = -1e30f;
            #pragma unroll
            for (int i2 = 0; i2 < 4; i2++) {
                float sc = s[j][i2] * scale +
                           mask[(size_t)(q0 + qg * 4 + j) * GG + k0 + kg + 16 * i2];
                s[j][i2] = sc;
                pm = fmaxf(pm, sc);
            }
            red[qg * 4 + j][kg] = pm;
        }
        __syncthreads();
        if (t < 64) {
            float rm = -1e30f;
            #pragma unroll
            for (int i2 = 0; i2 < 16; i2++) rm = fmaxf(rm, red[t][i2]);
            float om = m_sh[t];
            float nm = fmaxf(om, rm);
            al_sh[t] = __expf(om - nm);
            m_sh[t] = nm;
        }
        __syncthreads();
        #pragma unroll
        for (int j = 0; j < 4; j++) {
            float nm = m_sh[qg * 4 + j];
            float ps = 0.f;
            #pragma unroll
            for (int i2 = 0; i2 < 4; i2++) {
                float p = __expf(s[j][i2] - nm);
                Ps[qg * 4 + j][kg + 16 * i2] = p;
                ps += p;
            }
            red[qg * 4 + j][kg] = ps;
        }
        __syncthreads();
        if (t < 64) {
            float rs = 0.f;
            #pragma unroll
            for (int i2 = 0; i2 < 16; i2++) rs += red[t][i2];
            l_sh[t] = l_sh[t] * al_sh[t] + rs;
        }
        // PV: rescale and accumulate this tile's quarter of k
        #pragma unroll
        for (int j = 0; j < 4; j++) {
            float a = al_sh[qi0 + j];
            #pragma unroll
            for (int m2 = 0; m2 < 8; m2++) oacc[j][m2] *= a;
        }
        for (int n = 0; n < 16; n++) {
            int kj = wv * 16 + n;
            float p4[4];
            #pragma unroll
            for (int j = 0; j < 4; j++) p4[j] = Ps[qi0 + j][kj];
            float4 va = *(const float4*)&Vs[kj][dg0];
            float4 vb = *(const float4*)&Vs[kj][dg0 + 4];
            #pragma unroll
            for (int j = 0; j < 4; j++) {
                oacc[j][0] += p4[j] * va.x; oacc[j][1] += p4[j] * va.y;
                oacc[j][2] += p4[j] * va.z; oacc[j][3] += p4[j] * va.w;
                oacc[j][4] += p4[j] * vb.x; oacc[j][5] += p4[j] * vb.y;
                oacc[j][6] += p4[j] * vb.z; oacc[j][7] += p4[j] * vb.w;
            }
        }
    }
    __syncthreads();
    // combine 4 wave partials (reuse Ps as [64][32] buffer)
    float* Obuf = (float*)Ps;
    if (wv == 0) {
        #pragma unroll
        for (int j = 0; j < 4; j++)
            #pragma unroll
            for (int m2 = 0; m2 < 8; m2++)
                Obuf[(qi0 + j) * 32 + dg0 + m2] = oacc[j][m2];
    }
    __syncthreads();
    for (int w = 1; w < 4; w++) {
        if (wv == w) {
            #pragma unroll
            for (int j = 0; j < 4; j++)
                #pragma unroll
                for (int m2 = 0; m2 < 8; m2++)
                    Obuf[(qi0 + j) * 32 + dg0 + m2] += oacc[j][m2];
        }
        __syncthreads();
    }
    for (int i = t; i < 2048; i += 256) {
        int qi = i >> 5, d = i & 31;
        ctx[((size_t)b * GG + q0 + qi) * 64 + h * 32 + d] = Obuf[i] / l_sh[qi];
    }
}

// att = ctx @ Wout^T + b ; h1 = LN(out + att)    (4 rows/block, 1 wave per row)
__global__ void k_attn_out_ln(const float* __restrict__ ctxb, const float* __restrict__ outb,
                              const float* __restrict__ W, const float* __restrict__ bias,
                              const float* __restrict__ lg, const float* __restrict__ lb,
                              float* __restrict__ h1) {
    __shared__ float Wt[64][65];
    __shared__ float Cs[4][64];
    int t = threadIdx.x;
    for (int i = t; i < 4096; i += 256) Wt[i & 63][i >> 6] = W[i];
    int rr = t >> 6, lane = t & 63;
    int row = blockIdx.x * 4 + rr;
    Cs[rr][lane] = ctxb[row * 64 + lane];
    __syncthreads();
    float acc = bias[lane];
    const float* cr = Cs[rr];
    #pragma unroll 8
    for (int k = 0; k < 64; k++) acc += cr[k] * Wt[k][lane];
    float v = outb[row * 64 + lane] + acc;
    float s = v;
    for (int o = 32; o > 0; o >>= 1) s += __shfl_xor(s, o, 64);
    float mean = s * (1.f / 64.f);
    float d = v - mean;
    float sq = d * d;
    for (int o = 32; o > 0; o >>= 1) sq += __shfl_xor(sq, o, 64);
    float inv = rsqrtf(sq * (1.f / 64.f) + BNEPS);
    h1[row * 64 + lane] = d * inv * lg[lane] + lb[lane];
}

// enc = LN(h1 + ff); pred = enc . indv_w1[g] + indv_b1[g] + recon
__global__ void k_final(const float* __restrict__ h1, const float* __restrict__ ffo,
                        const float* __restrict__ lg, const float* __restrict__ lb,
                        const float* __restrict__ indvw, const float* __restrict__ indvb,
                        const float* __restrict__ hdc, const float* __restrict__ d2w,
                        const float* __restrict__ d2b, const float* __restrict__ x,
                        float* __restrict__ outp) {
    int t = threadIdx.x;
    int rr = t >> 6, lane = t & 63;
    int row = blockIdx.x * 4 + rr;
    int b = row >> 12, g = row & 4095;
    float v = h1[row * 64 + lane] + ffo[row * 64 + lane];
    float s = v;
    for (int o = 32; o > 0; o >>= 1) s += __shfl_xor(s, o, 64);
    float mean = s * (1.f / 64.f);
    float d = v - mean;
    float sq = d * d;
    for (int o = 32; o > 0; o >>= 1) sq += __shfl_xor(sq, o, 64);
    float inv = rsqrtf(sq * (1.f / 64.f) + BNEPS);
    float enc = d * inv * lg[lane] + lb[lane];
    float p = enc * indvw[g * 64 + lane];
    for (int o = 32; o > 0; o >>= 1) p += __shfl_xor(p, o, 64);
    float rc = 0.f;
    if (lane < 32) rc = hdc[b * 32 + lane] * d2w[g * 32 + lane];
    for (int o = 16; o > 0; o >>= 1) rc += __shfl_xor(rc, o, 64);
    if (lane == 0) {
        float recon = rc + d2b[g];
        if (x[row] == 0.f) recon = 0.f;
        outp[row] = p + indvb[g] + recon;
    }
}

// VAE encoder first layer: he[b,i] = relu(x[b,:] . W[i,:] + bias[i])
__global__ void k_vae_he(const float* __restrict__ x, const float* __restrict__ W,
                         const float* __restrict__ bias, float* he) {
    int b = blockIdx.x >> 5, i = blockIdx.x & 31;
    float s = 0.f;
    for (int g = threadIdx.x; g < 4096; g += 256) s += x[b * 4096 + g] * W[i * 4096 + g];
    __shared__ float ls[256];
    ls[threadIdx.x] = s;
    __syncthreads();
    for (int o = 128; o > 0; o >>= 1) {
        if (threadIdx.x < o) ls[threadIdx.x] += ls[threadIdx.x + o];
        __syncthreads();
    }
    if (threadIdx.x == 0) he[b * 32 + i] = fmaxf(ls[0] + bias[i], 0.f);
}

// VAE middle: mu/lv/z/kl + decoder layer 1 -> hdc.  single block x 128.
__global__ void k_vae_mid(const float* __restrict__ he,
                          const float* __restrict__ muw, const float* __restrict__ mub,
                          const float* __restrict__ lvw, const float* __restrict__ lvb,
                          const float* __restrict__ d1w, const float* __restrict__ d1b,
                          const float* __restrict__ eps, float* hdc, float* klout) {
    __shared__ float zs[64];
    int t = threadIdx.x;
    if (t < 64) {
        int b = t >> 4, l = t & 15;
        float mu = mub[l], lv = lvb[l];
        for (int i = 0; i < 32; i++) {
            float hv = he[b * 32 + i];
            mu += hv * muw[l * 32 + i];
            lv += hv * lvw[l * 32 + i];
        }
        zs[t] = mu + eps[t] * expf(0.5f * lv);
        float kterm = 1.f + lv - mu * mu - expf(lv);
        for (int o = 32; o > 0; o >>= 1) kterm += __shfl_xor(kterm, o, 64);
        if (t == 0) klout[0] = -0.5f * kterm * 0.25f;
    }
    __syncthreads();
    {
        int b = t >> 5, i = t & 31;
        float a = d1b[i];
        for (int l = 0; l < 16; l++) a += zs[b * 16 + l] * d1w[i * 16 + l];
        hdc[t] = fmaxf(a, 0.f);
    }
}

extern "C" void kernel_launch(void* const* d_in, const int* in_sizes, int n_in,
                              void* d_out, int out_size, void* d_ws, size_t ws_size,
                              hipStream_t stream) {
    const float* x        = (const float*)d_in[0];
    const int*   pert_idx = (const int*)  d_in[1];
    const float* mask     = (const float*)d_in[2];
    const int*   ei_co    = (const int*)  d_in[3];
    const float* w_co     = (const float*)d_in[4];
    const int*   ei_go    = (const int*)  d_in[5];
    const float* w_go     = (const float*)d_in[6];
    const float* gene_emb = (const float*)d_in[7];
    const float* emb_pos  = (const float*)d_in[8];
    const float* pert_tbl = (const float*)d_in[9];
    const float* sg_co_w  = (const float*)d_in[10];
    const float* sg_co_b  = (const float*)d_in[11];
    const float* sg_go_w  = (const float*)d_in[12];
    const float* sg_go_b  = (const float*)d_in[13];
    const float* bn_emb_g = (const float*)d_in[14];
    const float* bn_emb_b = (const float*)d_in[15];
    const float* etv1_w   = (const float*)d_in[16];
    const float* etv1_b   = (const float*)d_in[17];
    const float* etv1_g   = (const float*)d_in[18];
    const float* etv1_be  = (const float*)d_in[19];
    const float* etv2_w   = (const float*)d_in[20];
    const float* etv2_b   = (const float*)d_in[21];
    const float* etv2_g   = (const float*)d_in[22];
    const float* etv2_be  = (const float*)d_in[23];
    const float* pf1_w    = (const float*)d_in[24];
    const float* pf1_b    = (const float*)d_in[25];
    const float* pf1_g    = (const float*)d_in[26];
    const float* pf1_be   = (const float*)d_in[27];
    const float* pf2_w    = (const float*)d_in[28];
    const float* pf2_b    = (const float*)d_in[29];
    const float* pf2_g    = (const float*)d_in[30];
    const float* pf2_be   = (const float*)d_in[31];
    const float* rw1_w    = (const float*)d_in[32];
    const float* rw1_b    = (const float*)d_in[33];
    const float* rw1_g    = (const float*)d_in[34];
    const float* rw1_be   = (const float*)d_in[35];
    const float* rw2_w    = (const float*)d_in[36];
    const float* rw2_b    = (const float*)d_in[37];
    const float* rw2_g    = (const float*)d_in[38];
    const float* rw2_be   = (const float*)d_in[39];
    const float* bnpb_g   = (const float*)d_in[40];
    const float* bnpb_b   = (const float*)d_in[41];
    const float* ain_w    = (const float*)d_in[42];
    const float* ain_b    = (const float*)d_in[43];
    const float* aout_w   = (const float*)d_in[44];
    const float* aout_b   = (const float*)d_in[45];
    const float* ln1_g    = (const float*)d_in[46];
    const float* ln1_b    = (const float*)d_in[47];
    const float* ff1_w    = (const float*)d_in[48];
    const float* ff1_b    = (const float*)d_in[49];
    const float* ff2_w    = (const float*)d_in[50];
    const float* ff2_b    = (const float*)d_in[51];
    const float* ln2_g    = (const float*)d_in[52];
    const float* ln2_b    = (const float*)d_in[53];
    const float* indv_w   = (const float*)d_in[54];
    const float* indv_b   = (const float*)d_in[55];
    const float* ve1_w    = (const float*)d_in[56];
    const float* ve1_b    = (const float*)d_in[57];
    const float* vmu_w    = (const float*)d_in[58];
    const float* vmu_b    = (const float*)d_in[59];
    const float* vlv_w    = (const float*)d_in[60];
    const float* vlv_b    = (const float*)d_in[61];
    const float* vd1_w    = (const float*)d_in[62];
    const float* vd1_b    = (const float*)d_in[63];
    const float* vd2_w    = (const float*)d_in[64];
    const float* vd2_b    = (const float*)d_in[65];
    const float* veps     = (const float*)d_in[66];

    float* ws   = (float*)d_ws;
    float* outp = (float*)d_out;

    float* stm0 = ws + OF_STATS + 0 * 256; float* sti0 = stm0 + 128;
    float* stm1 = ws + OF_STATS + 1 * 256; float* sti1 = stm1 + 128;
    float* stm2 = ws + OF_STATS + 2 * 256; float* sti2 = stm2 + 128;
    float* stm3 = ws + OF_STATS + 3 * 256; float* sti3 = stm3 + 128;
    float* stm4 = ws + OF_STATS + 4 * 256; float* sti4 = stm4 + 128;
    float* stm5 = ws + OF_STATS + 5 * 256; float* sti5 = stm5 + 128;

    float* degco  = ws + OF_DEGCO;
    float* deggo  = ws + OF_DEGGO;
    float* pslot  = ws + OF_PSLOT;
    float* etot   = ws + OF_ETOT;
    float* hdc    = ws + OF_HDC;
    float* he     = ws + OF_HE;
    float* aggco  = ws + OF_AGGCO;
    float* basein = ws + OF_BASEIN;
    float* y1     = ws + OF_Y1;
    float* y2     = ws + OF_Y2;
    float* flat   = ws + OF_FLAT;
    float* yrw1   = ws + OF_RW1;
    float* yrw2   = ws + OF_RW2;
    float* outb   = ws + OF_OUT;
    float* qkv    = ws + OF_QKV;
    float* ctxb   = ws + OF_CTX;
    float* h1     = ws + OF_H1;
    float* fft    = ws + OF_FFT;
    float* ffo    = ws + OF_FFO;

    const int NG = BB * GG; // 16384

    // ---- co-graph SGConv + gene base ----
    k_fill<<<16, 256, 0, stream>>>(degco, 1.0f, GG);
    k_edge_deg<<<(E1N + 255) / 256, 256, 0, stream>>>(ei_co, w_co, degco, E1N);
    k_rsqrt_ip<<<16, 256, 0, stream>>>(degco, GG);
    k_agg_init<<<(GG * HH) / 256, 256, 0, stream>>>(emb_pos, degco, aggco, GG);
    k_edge_agg<<<(E1N * 64) / 256, 256, 0, stream>>>(ei_co, w_co, degco, emb_pos, aggco, E1N);
    k_colstats<<<64, 256, 0, stream>>>(gene_emb, GG, 64, stm0, sti0);
    k_base_combine<<<GG / 4, 256, 0, stream>>>(gene_emb, aggco, sg_co_w, sg_co_b,
                                               stm0, sti0, bn_emb_g, bn_emb_b, basein);
    // etv MLP
    k_gemm<<<GG / 32, 256, 0, stream>>>(basein, etv1_w, etv1_b, y1, GG, 64, 64,
                                        nullptr, nullptr, nullptr, nullptr, 0);
    k_colstats<<<64, 256, 0, stream>>>(y1, GG, 64, stm1, sti1);
    k_gemm<<<GG / 32, 256, 0, stream>>>(y1, etv2_w, etv2_b, y2, GG, 64, 64,
                                        stm1, sti1, etv1_g, etv1_be, 1);
    k_colstats<<<64, 256, 0, stream>>>(y2, GG, 64, stm2, sti2);

    // ---- go-graph SGConv (only 8 gathered rows) + pert MLP ----
    k_fill<<<16, 256, 0, stream>>>(deggo, 1.0f, PP);
    k_edge_deg<<<(E2N + 255) / 256, 256, 0, stream>>>(ei_go, w_go, deggo, E2N);
    k_rsqrt_ip<<<16, 256, 0, stream>>>(deggo, PP);
    k_pert_slots<<<1, 512, 0, stream>>>(pert_idx, pert_tbl, deggo, pslot);
    k_pert_edges<<<(E2N + 255) / 256, 256, 0, stream>>>(pert_idx, ei_go, w_go, deggo,
                                                        pert_tbl, pslot);
    k_pert_mlp<<<1, 256, 0, stream>>>(pslot, sg_go_w, sg_go_b,
                                      pf1_w, pf1_b, pf1_g, pf1_be,
                                      pf2_w, pf2_b, pf2_g, pf2_be, etot);

    // ---- fuse, rw MLP ----
    k_flatpre<<<(NG * HH) / 256, 256, 0, stream>>>(y2, etot, stm2, sti2, etv2_g, etv2_be, flat);
    k_colstats<<<64, 256, 0, stream>>>(flat, NG, 64, stm3, sti3);
    k_gemm<<<NG / 32, 256, 0, stream>>>(flat, rw1_w, rw1_b, yrw1, NG, 64, 128,
                                        stm3, sti3, bnpb_g, bnpb_b, 1);
    k_colstats<<<128, 256, 0, stream>>>(yrw1, NG, 128, stm4, sti4);
    k_gemm<<<NG / 32, 256, 0, stream>>>(yrw1, rw2_w, rw2_b, yrw2, NG, 128, 64,
                                        stm4, sti4, rw1_g, rw1_be, 1);
    k_colstats<<<64, 256, 0, stream>>>(yrw2, NG, 64, stm5, sti5);
    k_bn_apply<<<(NG * HH) / 256, 256, 0, stream>>>(yrw2, outb, NG * HH,
                                                    stm5, sti5, rw2_g, rw2_be);

    // ---- transformer ----
    k_gemm<<<NG / 32, 256, 0, stream>>>(outb, ain_w, ain_b, qkv, NG, 64, 192,
                                        nullptr, nullptr, nullptr, nullptr, 0);
    k_attn<<<dim3(GG / 64, BB * 2), 256, 0, stream>>>(qkv, mask, ctxb);
    k_attn_out_ln<<<NG / 4, 256, 0, stream>>>(ctxb, outb, aout_w, aout_b, ln1_g, ln1_b, h1);
    k_gemm<<<NG / 32, 256, 0, stream>>>(h1, ff1_w, ff1_b, fft, NG, 64, FFD,
                                        nullptr, nullptr, nullptr, nullptr, 0);
    k_gemm<<<NG / 32, 256, 0, stream>>>(fft, ff2_w, ff2_b, ffo, NG, FFD, 64,
                                        nullptr, nullptr, nullptr, nullptr, 1);

    // ---- VAE ----
    k_vae_he<<<128, 256, 0, stream>>>(x, ve1_w, ve1_b, he);
    k_vae_mid<<<1, 128, 0, stream>>>(he, vmu_w, vmu_b, vlv_w, vlv_b, vd1_w, vd1_b,
                                     veps, hdc, outp + NG);

    // ---- final: LN2 + per-gene head + recon ----
    k_final<<<NG / 4, 256, 0, stream>>>(h1, ffo, ln2_g, ln2_b, indv_w, indv_b,
                                        hdc, vd2_w, vd2_b, x, outp);
}

// Round 2
// 809.960 us; speedup vs baseline: 1.4017x; 1.4017x over previous
//
#include <hip/hip_runtime.h>
#include <math.h>

#define GG 4096
#define PP 4096
#define HH 64
#define BB 4
#define E1N 81920
#define E2N 81920
#define FFD 512
#define BNEPS 1e-5f

typedef unsigned short ushort_t;
typedef unsigned int uint_t;
using sh8 = __attribute__((ext_vector_type(8))) short;
using f4  = __attribute__((ext_vector_type(4))) float;

// ---------------- workspace layout (float offsets) ----------------
#define OF_STATS   0          // 6 slots x 256 (sum/mean[128] + sumsq/invstd[128])
#define OF_DEGCO   2048
#define OF_DEGGO   6144
#define OF_PSLOT   10240      // 8 x 64
#define OF_ETOT    10752      // 4 x 64
#define OF_HDC     11008      // 4 x 32
#define OF_HE      11136      // 4 x 32
#define OF_AGGCO   12288      // 4096 x 64
#define OF_BASEIN  274432     // 4096 x 64
#define OF_Y1      536576     // 4096 x 64
#define OF_Y2      798720     // 4096 x 64
#define OF_FLAT    1060864    // 16384 x 64
#define OF_RW1     2109440    // 16384 x 128
#define OF_RW2     4206592    // 16384 x 64
#define OF_OUT     5255168    // 16384 x 64
#define OF_QKV     6303744    // 16384 x 192
#define OF_CTX     9449472    // 16384 x 64
#define OF_H1      10498048   // 16384 x 64
#define OF_FFT     OF_FLAT    // 16384 x 512 (aliases FLAT..QKV; all dead by then)
#define OF_FFO     OF_CTX     // 16384 x 64  (aliases CTX, dead by then)
// bf16 attention buffers (alias dead fp32 regions; prep runs after those die)
#define OF_QB      OF_AGGCO   // 8*4096*32 ushort = 524288 floats
#define OF_KB      (OF_AGGCO + 524288)
#define OF_VT      OF_FLAT    // 8*32*4096 ushort = 524288 floats (dead before FFT use)

__device__ inline ushort_t f2b(float f) {
    uint_t u = __builtin_bit_cast(uint_t, f);
    u += 0x7FFFu + ((u >> 16) & 1u);
    return (ushort_t)(u >> 16);
}

__device__ inline void gld16(const void* gptr, void* lptr) {
    __builtin_amdgcn_global_load_lds(
        (const __attribute__((address_space(1))) uint_t*)gptr,
        (__attribute__((address_space(3))) uint_t*)lptr, 16, 0, 0);
}

// ---------------- simple utility kernels ----------------
__global__ void k_fill(float* p, float v, int n) {
    int i = blockIdx.x * 256 + threadIdx.x;
    if (i < n) p[i] = v;
}

__global__ void k_edge_deg(const int* __restrict__ ei, const float* __restrict__ w,
                           float* deg, int E) {
    int e = blockIdx.x * 256 + threadIdx.x;
    if (e < E) atomicAdd(&deg[ei[E + e]], w[e]);
}

__global__ void k_rsqrt_ip(float* p, int n) {
    int i = blockIdx.x * 256 + threadIdx.x;
    if (i < n) p[i] = rsqrtf(p[i]);
}

__global__ void k_agg_init(const float* __restrict__ x, const float* __restrict__ dinv,
                           float* agg, int n) {
    int i = blockIdx.x * 256 + threadIdx.x;
    if (i < n * HH) {
        int node = i >> 6;
        float di = dinv[node];
        agg[i] = x[i] * di * di;
    }
}

__global__ void k_edge_agg(const int* __restrict__ ei, const float* __restrict__ w,
                           const float* __restrict__ dinv, const float* __restrict__ x,
                           float* agg, int E) {
    int gid = blockIdx.x * 256 + threadIdx.x;
    int e = gid >> 6, h = gid & 63;
    if (e < E) {
        int src = ei[e], dst = ei[E + e];
        float norm = dinv[dst] * w[e] * dinv[src];
        atomicAdd(&agg[dst * HH + h], norm * x[src * HH + h]);
    }
}

// ---- two-phase coalesced column stats ----
__global__ void k_cs_part(const float* __restrict__ X, int N, int C,
                          float* sum, float* sumsq) {
    int t = threadIdx.x;
    int col = t & (C - 1);
    int ro = t / C;
    int stride = 256 / C;
    int rows = N >> 7;            // N/128
    int r0 = blockIdx.x * rows;
    float s = 0.f, q = 0.f;
    for (int r = r0 + ro; r < r0 + rows; r += stride) {
        float v = X[r * C + col];
        s += v; q += v * v;
    }
    __shared__ float ls[256], lq[256];
    ls[t] = s; lq[t] = q;
    __syncthreads();
    if (t < C) {
        for (int j = t + C; j < 256; j += C) { s += ls[j]; q += lq[j]; }
        atomicAdd(&sum[t], s);
        atomicAdd(&sumsq[t], q);
    }
}

__global__ void k_cs_fin(float* sum, float* sumsq, int N) {
    int c = threadIdx.x;
    float m = sum[c] / (float)N;
    float v = sumsq[c] / (float)N - m * m;
    sum[c] = m;
    sumsq[c] = rsqrtf(v + BNEPS);
}

// base_in = relu(bn(gene_emb)) + 0.2*(agg @ Wco^T + bco)
__global__ void k_base_combine(const float* __restrict__ gene_emb, const float* __restrict__ agg,
                               const float* __restrict__ W, const float* __restrict__ bias,
                               const float* __restrict__ m, const float* __restrict__ is,
                               const float* __restrict__ bg, const float* __restrict__ bb,
                               float* out) {
    __shared__ float Wt[64][65];
    __shared__ float a[4][64];
    int t = threadIdx.x;
    for (int i = t; i < 4096; i += 256) Wt[i & 63][i >> 6] = W[i];
    int rr = t >> 6, h = t & 63;
    int g = blockIdx.x * 4 + rr;
    a[rr][h] = agg[g * 64 + h];
    __syncthreads();
    float y = bias[h];
    const float* ar = a[rr];
    #pragma unroll 8
    for (int k = 0; k < 64; k++) y += ar[k] * Wt[k][h];
    float v = gene_emb[g * 64 + h];
    v = (v - m[h]) * is[h] * bg[h] + bb[h];
    v = fmaxf(v, 0.f);
    out[g * 64 + h] = v + 0.2f * y;
}

// generic GEMM: Y[N,Cout] = f(X[N,Cin]) @ W[Cout,Cin]^T + bias
__launch_bounds__(256)
__global__ void k_gemm(const float* __restrict__ X, const float* __restrict__ W,
                       const float* __restrict__ bias, float* __restrict__ Y,
                       int N, int Cin, int Cout,
                       const float* __restrict__ bnm, const float* __restrict__ bni,
                       const float* __restrict__ bng, const float* __restrict__ bnb,
                       int relu_in) {
    __shared__ float Xs[32][129];
    __shared__ float Wt[128][65];
    int row0 = blockIdx.x * 32;
    int c0 = threadIdx.x & 63, rg = threadIdx.x >> 6;
    for (int cb = 0; cb < Cout; cb += 64) {
        float acc[8];
        #pragma unroll
        for (int j = 0; j < 8; j++) acc[j] = 0.f;
        for (int k0 = 0; k0 < Cin; k0 += 128) {
            int kc = (Cin - k0 < 128) ? (Cin - k0) : 128;
            __syncthreads();
            for (int i = threadIdx.x; i < 32 * kc; i += 256) {
                int r, k;
                if (kc == 128) { r = i >> 7; k = i & 127; } else { r = i >> 6; k = i & 63; }
                float v = X[(row0 + r) * Cin + k0 + k];
                if (bnm) {
                    int c = k0 + k;
                    v = (v - bnm[c]) * bni[c] * bng[c] + bnb[c];
                }
                if (relu_in) v = fmaxf(v, 0.f);
                Xs[r][k] = v;
            }
            for (int i = threadIdx.x; i < 64 * kc; i += 256) {
                int co, k;
                if (kc == 128) { co = i >> 7; k = i & 127; } else { co = i >> 6; k = i & 63; }
                Wt[k][co] = W[(cb + co) * Cin + k0 + k];
            }
            __syncthreads();
            #pragma unroll 4
            for (int k = 0; k < kc; k++) {
                float w = Wt[k][c0];
                #pragma unroll
                for (int j = 0; j < 8; j++) acc[j] += Xs[rg * 8 + j][k] * w;
            }
        }
        float bi = bias[cb + c0];
        #pragma unroll
        for (int j = 0; j < 8; j++)
            Y[(row0 + rg * 8 + j) * Cout + cb + c0] = acc[j] + bi;
    }
}

__global__ void k_bn_apply(const float* __restrict__ X, float* Y, int total,
                           const float* __restrict__ m, const float* __restrict__ is,
                           const float* __restrict__ g, const float* __restrict__ b) {
    int i = blockIdx.x * 256 + threadIdx.x;
    if (i < total) {
        int c = i & 63;
        Y[i] = (X[i] - m[c]) * is[c] * g[c] + b[c];
    }
}

__global__ void k_flatpre(const float* __restrict__ y2, const float* __restrict__ etot,
                          const float* __restrict__ m, const float* __restrict__ is,
                          const float* __restrict__ g2, const float* __restrict__ b2,
                          float* out) {
    int i = blockIdx.x * 256 + threadIdx.x;
    int h = i & 63;
    int b = i >> 18;
    int gh = i & (GG * HH - 1);
    float v = y2[gh];
    v = (v - m[h]) * is[h] * g2[h] + b2[h];
    out[i] = v + etot[b * 64 + h];
}

__global__ void k_pert_slots(const int* __restrict__ pidx, const float* __restrict__ tbl,
                             const float* __restrict__ dinv, float* pslot) {
    int i = threadIdx.x;
    int s = i >> 6, h = i & 63;
    int n = pidx[s];
    float di = dinv[n];
    pslot[i] = tbl[n * 64 + h] * di * di;
}

__global__ void k_pert_edges(const int* __restrict__ pidx, const int* __restrict__ ei,
                             const float* __restrict__ w, const float* __restrict__ dinv,
                             const float* __restrict__ tbl, float* pslot) {
    int e = blockIdx.x * 256 + threadIdx.x;
    if (e >= E2N) return;
    int dst = ei[E2N + e];
    int src = ei[e];
    for (int s = 0; s < 8; s++) {
        if (pidx[s] == dst) {
            float norm = dinv[dst] * w[e] * dinv[src];
            for (int h = 0; h < 64; h++)
                atomicAdd(&pslot[s * 64 + h], norm * tbl[src * 64 + h]);
        }
    }
}

__global__ void k_pert_mlp(const float* __restrict__ pslot,
                           const float* __restrict__ gw, const float* __restrict__ gb,
                           const float* __restrict__ w1, const float* __restrict__ b1,
                           const float* __restrict__ g1, const float* __restrict__ be1,
                           const float* __restrict__ w2, const float* __restrict__ b2,
                           const float* __restrict__ g2, const float* __restrict__ be2,
                           float* etot) {
    __shared__ float pge[8][64], psum[4][64], y[4][64], mh[64], ih[64];
    int t = threadIdx.x;
    for (int j = t; j < 512; j += 256) {
        int s = j >> 6, h = j & 63;
        float acc = gb[h];
        for (int k = 0; k < 64; k++) acc += pslot[s * 64 + k] * gw[h * 64 + k];
        pge[s][h] = acc;
    }
    __syncthreads();
    { int b = t >> 6, h = t & 63; psum[b][h] = pge[2 * b][h] + pge[2 * b + 1][h]; }
    __syncthreads();
    { int b = t >> 6, h = t & 63;
      float acc = b1[h];
      for (int k = 0; k < 64; k++) acc += psum[b][k] * w1[h * 64 + k];
      y[b][h] = acc; }
    __syncthreads();
    if (t < 64) {
        float s = 0.f, sq = 0.f;
        for (int b = 0; b < 4; b++) { float v = y[b][t]; s += v; sq += v * v; }
        float m = s * 0.25f;
        mh[t] = m; ih[t] = rsqrtf(sq * 0.25f - m * m + BNEPS);
    }
    __syncthreads();
    { int b = t >> 6, h = t & 63;
      float v = (y[b][h] - mh[h]) * ih[h] * g1[h] + be1[h];
      psum[b][h] = fmaxf(v, 0.f); }
    __syncthreads();
    { int b = t >> 6, h = t & 63;
      float acc = b2[h];
      for (int k = 0; k < 64; k++) acc += psum[b][k] * w2[h * 64 + k];
      y[b][h] = acc; }
    __syncthreads();
    if (t < 64) {
        float s = 0.f, sq = 0.f;
        for (int b = 0; b < 4; b++) { float v = y[b][t]; s += v; sq += v * v; }
        float m = s * 0.25f;
        mh[t] = m; ih[t] = rsqrtf(sq * 0.25f - m * m + BNEPS);
    }
    __syncthreads();
    { int b = t >> 6, h = t & 63;
      etot[b * 64 + h] = (y[b][h] - mh[h]) * ih[h] * g2[h] + be2[h]; }
}

// ---- qkv prep: fp32 [B*G][192] -> bf16 Qb/Kb [bh][4096][32], Vt [bh][32][4096]
__global__ void k_qkv_prep(const float* __restrict__ qkv, ushort_t* __restrict__ Qb,
                           ushort_t* __restrict__ Kb, ushort_t* __restrict__ Vtg) {
    const int bh = blockIdx.y, b = bh >> 1, h = bh & 1;
    const int g0 = blockIdx.x * 64;
    const int t = threadIdx.x;
    const int row = t >> 2, d0 = (t & 3) * 8;
    __shared__ ushort_t Lv[64][33];
    size_t base = ((size_t)(b * GG + g0 + row)) * 192 + h * 32 + d0;
    union { ushort_t u[8]; uint4 v; } pk;
    // Q
    {
        float4 a = *(const float4*)&qkv[base];
        float4 c = *(const float4*)&qkv[base + 4];
        pk.u[0] = f2b(a.x); pk.u[1] = f2b(a.y); pk.u[2] = f2b(a.z); pk.u[3] = f2b(a.w);
        pk.u[4] = f2b(c.x); pk.u[5] = f2b(c.y); pk.u[6] = f2b(c.z); pk.u[7] = f2b(c.w);
        *(uint4*)&Qb[((size_t)bh * GG + g0 + row) * 32 + d0] = pk.v;
    }
    // K
    {
        float4 a = *(const float4*)&qkv[base + 64];
        float4 c = *(const float4*)&qkv[base + 68];
        pk.u[0] = f2b(a.x); pk.u[1] = f2b(a.y); pk.u[2] = f2b(a.z); pk.u[3] = f2b(a.w);
        pk.u[4] = f2b(c.x); pk.u[5] = f2b(c.y); pk.u[6] = f2b(c.z); pk.u[7] = f2b(c.w);
        *(uint4*)&Kb[((size_t)bh * GG + g0 + row) * 32 + d0] = pk.v;
    }
    // V -> LDS tile -> transposed out
    {
        float4 a = *(const float4*)&qkv[base + 128];
        float4 c = *(const float4*)&qkv[base + 132];
        Lv[row][d0 + 0] = f2b(a.x); Lv[row][d0 + 1] = f2b(a.y);
        Lv[row][d0 + 2] = f2b(a.z); Lv[row][d0 + 3] = f2b(a.w);
        Lv[row][d0 + 4] = f2b(c.x); Lv[row][d0 + 5] = f2b(c.y);
        Lv[row][d0 + 6] = f2b(c.z); Lv[row][d0 + 7] = f2b(c.w);
    }
    __syncthreads();
    {
        int d = t >> 3, koff = (t & 7) * 8;
        #pragma unroll
        for (int j = 0; j < 8; j++) pk.u[j] = Lv[koff + j][d];
        *(uint4*)&Vtg[((size_t)bh * 32 + d) * GG + g0 + koff] = pk.v;
    }
}

// ---- MFMA flash attention ----
// grid (G/64, B*NH), block 256 = 4 waves; wave w owns q rows [q0+16w, q0+16w+16)
__launch_bounds__(256)
__global__ void k_attn_mfma(const ushort_t* __restrict__ Qb, const ushort_t* __restrict__ Kb,
                            const ushort_t* __restrict__ Vtg, const float* __restrict__ mask,
                            float* __restrict__ ctx) {
    __shared__ ushort_t Ql[2048];      // frag-major [w][lane][8]
    __shared__ ushort_t Kl[2048];      // [i2][lane][8]
    __shared__ ushort_t Vl[2048];      // [(kstep*2+nt)][lane][8]
    __shared__ ushort_t Ps[4][1024];   // per-wave [kstep][lane][8]

    const int bh = blockIdx.y, b = bh >> 1, h = bh & 1;
    const int q0 = blockIdx.x * 64;
    const int t = threadIdx.x;
    const int lane = t & 63, w = t >> 6;
    const int l15 = lane & 15, quad = lane >> 4;
    const float scale = 0.17677669529663687f; // 1/sqrt(32)

    // stage Q (frag-major): thread t -> 16B chunk
    {
        const ushort_t* g = Qb + ((size_t)bh * GG + q0 + (t >> 6) * 16 + (t & 15)) * 32
                               + ((t >> 4) & 3) * 8;
        gld16(g, &Ql[t * 8]);
    }

    f4 O0 = {0.f, 0.f, 0.f, 0.f}, O1 = {0.f, 0.f, 0.f, 0.f};
    float mr[4], lr[4];
    #pragma unroll
    for (int r = 0; r < 4; r++) { mr[r] = -1e30f; lr[r] = 0.f; }
    sh8 qf;

    for (int k0 = 0; k0 < GG; k0 += 64) {
        __syncthreads();
        {
            const ushort_t* gk = Kb + ((size_t)bh * GG + k0 + (t >> 6) * 16 + (t & 15)) * 32
                                    + ((t >> 4) & 3) * 8;
            gld16(gk, &Kl[t * 8]);
            int kstep = t >> 7, nt = (t >> 6) & 1;
            const ushort_t* gv = Vtg + ((size_t)bh * 32 + nt * 16 + (t & 15)) * GG
                                     + k0 + kstep * 32 + ((t >> 4) & 3) * 8;
            gld16(gv, &Vl[t * 8]);
        }
        __syncthreads();
        if (k0 == 0) qf = *(const sh8*)&Ql[(w * 64 + lane) * 8];

        // QK^T: 4 MFMAs -> S[q=quad*4+r][key=k0+i2*16+l15]
        f4 s[4];
        #pragma unroll
        for (int i2 = 0; i2 < 4; i2++) {
            sh8 kf = *(const sh8*)&Kl[(i2 * 64 + lane) * 8];
            f4 z = {0.f, 0.f, 0.f, 0.f};
            s[i2] = __builtin_amdgcn_mfma_f32_16x16x32_bf16(qf, kf, z, 0, 0, 0);
        }
        // scale + mask + row max
        const float* mbase = mask + (size_t)(q0 + w * 16 + quad * 4) * GG + k0 + l15;
        float mx[4];
        #pragma unroll
        for (int r = 0; r < 4; r++) {
            float pm = -1e30f;
            #pragma unroll
            for (int i2 = 0; i2 < 4; i2++) {
                float sc = s[i2][r] * scale + mbase[(size_t)r * GG + i2 * 16];
                s[i2][r] = sc;
                pm = fmaxf(pm, sc);
            }
            mx[r] = pm;
        }
        #pragma unroll
        for (int off = 1; off < 16; off <<= 1) {
            #pragma unroll
            for (int r = 0; r < 4; r++) mx[r] = fmaxf(mx[r], __shfl_xor(mx[r], off, 64));
        }
        float al[4];
        #pragma unroll
        for (int r = 0; r < 4; r++) {
            float nm = fmaxf(mr[r], mx[r]);
            al[r] = __expf(mr[r] - nm);
            mr[r] = nm;
        }
        // P = exp(S - m), row sums
        float rs[4];
        #pragma unroll
        for (int r = 0; r < 4; r++) {
            float ss = 0.f;
            #pragma unroll
            for (int i2 = 0; i2 < 4; i2++) {
                float p = __expf(s[i2][r] - mr[r]);
                s[i2][r] = p;
                ss += p;
            }
            rs[r] = ss;
        }
        #pragma unroll
        for (int off = 1; off < 16; off <<= 1) {
            #pragma unroll
            for (int r = 0; r < 4; r++) rs[r] += __shfl_xor(rs[r], off, 64);
        }
        #pragma unroll
        for (int r = 0; r < 4; r++) {
            lr[r] = lr[r] * al[r] + rs[r];
            O0[r] *= al[r];
            O1[r] *= al[r];
        }
        // P (C-layout) -> Ps (A-frag layout), bf16
        #pragma unroll
        for (int i2 = 0; i2 < 4; i2++) {
            int bofs = (i2 >> 1) * 512 + (((i2 & 1) * 2 + (l15 >> 3)) * 16) * 8 + (l15 & 7);
            #pragma unroll
            for (int r = 0; r < 4; r++)
                Ps[w][bofs + (quad * 4 + r) * 8] = f2b(s[i2][r]);
        }
        // PV: 4 MFMAs
        #pragma unroll
        for (int kstep = 0; kstep < 2; kstep++) {
            sh8 pf = *(const sh8*)&Ps[w][(kstep * 64 + lane) * 8];
            sh8 vf0 = *(const sh8*)&Vl[((kstep * 2 + 0) * 64 + lane) * 8];
            sh8 vf1 = *(const sh8*)&Vl[((kstep * 2 + 1) * 64 + lane) * 8];
            O0 = __builtin_amdgcn_mfma_f32_16x16x32_bf16(pf, vf0, O0, 0, 0, 0);
            O1 = __builtin_amdgcn_mfma_f32_16x16x32_bf16(pf, vf1, O1, 0, 0, 0);
        }
    }
    // epilogue
    #pragma unroll
    for (int r = 0; r < 4; r++) {
        float inv = 1.0f / lr[r];
        int q = q0 + w * 16 + quad * 4 + r;
        size_t o = ((size_t)b * GG + q) * 64 + h * 32 + l15;
        ctx[o] = O0[r] * inv;
        ctx[o + 16] = O1[r] * inv;
    }
}

__global__ void k_attn_out_ln(const float* __restrict__ ctxb, const float* __restrict__ outb,
                              const float* __restrict__ W, const float* __restrict__ bias,
                              const float* __restrict__ lg, const float* __restrict__ lb,
                              float* __restrict__ h1) {
    __shared__ float Wt[64][65];
    __shared__ float Cs[4][64];
    int t = threadIdx.x;
    for (int i = t; i < 4096; i += 256) Wt[i & 63][i >> 6] = W[i];
    int rr = t >> 6, lane = t & 63;
    int row = blockIdx.x * 4 + rr;
    Cs[rr][lane] = ctxb[row * 64 + lane];
    __syncthreads();
    float acc = bias[lane];
    const float* cr = Cs[rr];
    #pragma unroll 8
    for (int k = 0; k < 64; k++) acc += cr[k] * Wt[k][lane];
    float v = outb[row * 64 + lane] + acc;
    float s = v;
    for (int o = 32; o > 0; o >>= 1) s += __shfl_xor(s, o, 64);
    float mean = s * (1.f / 64.f);
    float d = v - mean;
    float sq = d * d;
    for (int o = 32; o > 0; o >>= 1) sq += __shfl_xor(sq, o, 64);
    float inv = rsqrtf(sq * (1.f / 64.f) + BNEPS);
    h1[row * 64 + lane] = d * inv * lg[lane] + lb[lane];
}

__global__ void k_final(const float* __restrict__ h1, const float* __restrict__ ffo,
                        const float* __restrict__ lg, const float* __restrict__ lb,
                        const float* __restrict__ indvw, const float* __restrict__ indvb,
                        const float* __restrict__ hdc, const float* __restrict__ d2w,
                        const float* __restrict__ d2b, const float* __restrict__ x,
                        float* __restrict__ outp) {
    int t = threadIdx.x;
    int rr = t >> 6, lane = t & 63;
    int row = blockIdx.x * 4 + rr;
    int b = row >> 12, g = row & 4095;
    float v = h1[row * 64 + lane] + ffo[row * 64 + lane];
    float s = v;
    for (int o = 32; o > 0; o >>= 1) s += __shfl_xor(s, o, 64);
    float mean = s * (1.f / 64.f);
    float d = v - mean;
    float sq = d * d;
    for (int o = 32; o > 0; o >>= 1) sq += __shfl_xor(sq, o, 64);
    float inv = rsqrtf(sq * (1.f / 64.f) + BNEPS);
    float enc = d * inv * lg[lane] + lb[lane];
    float p = enc * indvw[g * 64 + lane];
    for (int o = 32; o > 0; o >>= 1) p += __shfl_xor(p, o, 64);
    float rc = 0.f;
    if (lane < 32) rc = hdc[b * 32 + lane] * d2w[g * 32 + lane];
    for (int o = 16; o > 0; o >>= 1) rc += __shfl_xor(rc, o, 64);
    if (lane == 0) {
        float recon = rc + d2b[g];
        if (x[row] == 0.f) recon = 0.f;
        outp[row] = p + indvb[g] + recon;
    }
}

__global__ void k_vae_he(const float* __restrict__ x, const float* __restrict__ W,
                         const float* __restrict__ bias, float* he) {
    int b = blockIdx.x >> 5, i = blockIdx.x & 31;
    float s = 0.f;
    for (int g = threadIdx.x; g < 4096; g += 256) s += x[b * 4096 + g] * W[i * 4096 + g];
    __shared__ float ls[256];
    ls[threadIdx.x] = s;
    __syncthreads();
    for (int o = 128; o > 0; o >>= 1) {
        if (threadIdx.x < o) ls[threadIdx.x] += ls[threadIdx.x + o];
        __syncthreads();
    }
    if (threadIdx.x == 0) he[b * 32 + i] = fmaxf(ls[0] + bias[i], 0.f);
}

__global__ void k_vae_mid(const float* __restrict__ he,
                          const float* __restrict__ muw, const float* __restrict__ mub,
                          const float* __restrict__ lvw, const float* __restrict__ lvb,
                          const float* __restrict__ d1w, const float* __restrict__ d1b,
                          const float* __restrict__ eps, float* hdc, float* klout) {
    __shared__ float zs[64];
    int t = threadIdx.x;
    if (t < 64) {
        int b = t >> 4, l = t & 15;
        float mu = mub[l], lv = lvb[l];
        for (int i = 0; i < 32; i++) {
            float hv = he[b * 32 + i];
            mu += hv * muw[l * 32 + i];
            lv += hv * lvw[l * 32 + i];
        }
        zs[t] = mu + eps[t] * expf(0.5f * lv);
        float kterm = 1.f + lv - mu * mu - expf(lv);
        for (int o = 32; o > 0; o >>= 1) kterm += __shfl_xor(kterm, o, 64);
        if (t == 0) klout[0] = -0.5f * kterm * 0.25f;
    }
    __syncthreads();
    {
        int b = t >> 5, i = t & 31;
        float a = d1b[i];
        for (int l = 0; l < 16; l++) a += zs[b * 16 + l] * d1w[i * 16 + l];
        hdc[t] = fmaxf(a, 0.f);
    }
}

extern "C" void kernel_launch(void* const* d_in, const int* in_sizes, int n_in,
                              void* d_out, int out_size, void* d_ws, size_t ws_size,
                              hipStream_t stream) {
    const float* x        = (const float*)d_in[0];
    const int*   pert_idx = (const int*)  d_in[1];
    const float* mask     = (const float*)d_in[2];
    const int*   ei_co    = (const int*)  d_in[3];
    const float* w_co     = (const float*)d_in[4];
    const int*   ei_go    = (const int*)  d_in[5];
    const float* w_go     = (const float*)d_in[6];
    const float* gene_emb = (const float*)d_in[7];
    const float* emb_pos  = (const float*)d_in[8];
    const float* pert_tbl = (const float*)d_in[9];
    const float* sg_co_w  = (const float*)d_in[10];
    const float* sg_co_b  = (const float*)d_in[11];
    const float* sg_go_w  = (const float*)d_in[12];
    const float* sg_go_b  = (const float*)d_in[13];
    const float* bn_emb_g = (const float*)d_in[14];
    const float* bn_emb_b = (const float*)d_in[15];
    const float* etv1_w   = (const float*)d_in[16];
    const float* etv1_b   = (const float*)d_in[17];
    const float* etv1_g   = (const float*)d_in[18];
    const float* etv1_be  = (const float*)d_in[19];
    const float* etv2_w   = (const float*)d_in[20];
    const float* etv2_b   = (const float*)d_in[21];
    const float* etv2_g   = (const float*)d_in[22];
    const float* etv2_be  = (const float*)d_in[23];
    const float* pf1_w    = (const float*)d_in[24];
    const float* pf1_b    = (const float*)d_in[25];
    const float* pf1_g    = (const float*)d_in[26];
    const float* pf1_be   = (const float*)d_in[27];
    const float* pf2_w    = (const float*)d_in[28];
    const float* pf2_b    = (const float*)d_in[29];
    const float* pf2_g    = (const float*)d_in[30];
    const float* pf2_be   = (const float*)d_in[31];
    const float* rw1_w    = (const float*)d_in[32];
    const float* rw1_b    = (const float*)d_in[33];
    const float* rw1_g    = (const float*)d_in[34];
    const float* rw1_be   = (const float*)d_in[35];
    const float* rw2_w    = (const float*)d_in[36];
    const float* rw2_b    = (const float*)d_in[37];
    const float* rw2_g    = (const float*)d_in[38];
    const float* rw2_be   = (const float*)d_in[39];
    const float* bnpb_g   = (const float*)d_in[40];
    const float* bnpb_b   = (const float*)d_in[41];
    const float* ain_w    = (const float*)d_in[42];
    const float* ain_b    = (const float*)d_in[43];
    const float* aout_w   = (const float*)d_in[44];
    const float* aout_b   = (const float*)d_in[45];
    const float* ln1_g    = (const float*)d_in[46];
    const float* ln1_b    = (const float*)d_in[47];
    const float* ff1_w    = (const float*)d_in[48];
    const float* ff1_b    = (const float*)d_in[49];
    const float* ff2_w    = (const float*)d_in[50];
    const float* ff2_b    = (const float*)d_in[51];
    const float* ln2_g    = (const float*)d_in[52];
    const float* ln2_b    = (const float*)d_in[53];
    const float* indv_w   = (const float*)d_in[54];
    const float* indv_b   = (const float*)d_in[55];
    const float* ve1_w    = (const float*)d_in[56];
    const float* ve1_b    = (const float*)d_in[57];
    const float* vmu_w    = (const float*)d_in[58];
    const float* vmu_b    = (const float*)d_in[59];
    const float* vlv_w    = (const float*)d_in[60];
    const float* vlv_b    = (const float*)d_in[61];
    const float* vd1_w    = (const float*)d_in[62];
    const float* vd1_b    = (const float*)d_in[63];
    const float* vd2_w    = (const float*)d_in[64];
    const float* vd2_b    = (const float*)d_in[65];
    const float* veps     = (const float*)d_in[66];

    float* ws   = (float*)d_ws;
    float* outp = (float*)d_out;

    float* stm0 = ws + OF_STATS + 0 * 256; float* sti0 = stm0 + 128;
    float* stm1 = ws + OF_STATS + 1 * 256; float* sti1 = stm1 + 128;
    float* stm2 = ws + OF_STATS + 2 * 256; float* sti2 = stm2 + 128;
    float* stm3 = ws + OF_STATS + 3 * 256; float* sti3 = stm3 + 128;
    float* stm4 = ws + OF_STATS + 4 * 256; float* sti4 = stm4 + 128;
    float* stm5 = ws + OF_STATS + 5 * 256; float* sti5 = stm5 + 128;

    float* degco  = ws + OF_DEGCO;
    float* deggo  = ws + OF_DEGGO;
    float* pslot  = ws + OF_PSLOT;
    float* etot   = ws + OF_ETOT;
    float* hdc    = ws + OF_HDC;
    float* he     = ws + OF_HE;
    float* aggco  = ws + OF_AGGCO;
    float* basein = ws + OF_BASEIN;
    float* y1     = ws + OF_Y1;
    float* y2     = ws + OF_Y2;
    float* flat   = ws + OF_FLAT;
    float* yrw1   = ws + OF_RW1;
    float* yrw2   = ws + OF_RW2;
    float* outb   = ws + OF_OUT;
    float* qkv    = ws + OF_QKV;
    float* ctxb   = ws + OF_CTX;
    float* h1     = ws + OF_H1;
    float* fft    = ws + OF_FFT;
    float* ffo    = ws + OF_FFO;
    ushort_t* Qb  = (ushort_t*)(ws + OF_QB);
    ushort_t* Kb  = (ushort_t*)(ws + OF_KB);
    ushort_t* Vt  = (ushort_t*)(ws + OF_VT);

    const int NG = BB * GG; // 16384

    // zero stats accumulators
    k_fill<<<8, 256, 0, stream>>>(ws + OF_STATS, 0.0f, 2048);

    // ---- co-graph SGConv + gene base ----
    k_fill<<<16, 256, 0, stream>>>(degco, 1.0f, GG);
    k_edge_deg<<<(E1N + 255) / 256, 256, 0, stream>>>(ei_co, w_co, degco, E1N);
    k_rsqrt_ip<<<16, 256, 0, stream>>>(degco, GG);
    k_agg_init<<<(GG * HH) / 256, 256, 0, stream>>>(emb_pos, degco, aggco, GG);
    k_edge_agg<<<(E1N * 64) / 256, 256, 0, stream>>>(ei_co, w_co, degco, emb_pos, aggco, E1N);
    k_cs_part<<<128, 256, 0, stream>>>(gene_emb, GG, 64, stm0, sti0);
    k_cs_fin<<<1, 64, 0, stream>>>(stm0, sti0, GG);
    k_base_combine<<<GG / 4, 256, 0, stream>>>(gene_emb, aggco, sg_co_w, sg_co_b,
                                               stm0, sti0, bn_emb_g, bn_emb_b, basein);
    // etv MLP
    k_gemm<<<GG / 32, 256, 0, stream>>>(basein, etv1_w, etv1_b, y1, GG, 64, 64,
                                        nullptr, nullptr, nullptr, nullptr, 0);
    k_cs_part<<<128, 256, 0, stream>>>(y1, GG, 64, stm1, sti1);
    k_cs_fin<<<1, 64, 0, stream>>>(stm1, sti1, GG);
    k_gemm<<<GG / 32, 256, 0, stream>>>(y1, etv2_w, etv2_b, y2, GG, 64, 64,
                                        stm1, sti1, etv1_g, etv1_be, 1);
    k_cs_part<<<128, 256, 0, stream>>>(y2, GG, 64, stm2, sti2);
    k_cs_fin<<<1, 64, 0, stream>>>(stm2, sti2, GG);

    // ---- go-graph SGConv (8 gathered rows) + pert MLP ----
    k_fill<<<16, 256, 0, stream>>>(deggo, 1.0f, PP);
    k_edge_deg<<<(E2N + 255) / 256, 256, 0, stream>>>(ei_go, w_go, deggo, E2N);
    k_rsqrt_ip<<<16, 256, 0, stream>>>(deggo, PP);
    k_pert_slots<<<1, 512, 0, stream>>>(pert_idx, pert_tbl, deggo, pslot);
    k_pert_edges<<<(E2N + 255) / 256, 256, 0, stream>>>(pert_idx, ei_go, w_go, deggo,
                                                        pert_tbl, pslot);
    k_pert_mlp<<<1, 256, 0, stream>>>(pslot, sg_go_w, sg_go_b,
                                      pf1_w, pf1_b, pf1_g, pf1_be,
                                      pf2_w, pf2_b, pf2_g, pf2_be, etot);

    // ---- fuse, rw MLP ----
    k_flatpre<<<(NG * HH) / 256, 256, 0, stream>>>(y2, etot, stm2, sti2, etv2_g, etv2_be, flat);
    k_cs_part<<<128, 256, 0, stream>>>(flat, NG, 64, stm3, sti3);
    k_cs_fin<<<1, 64, 0, stream>>>(stm3, sti3, NG);
    k_gemm<<<NG / 32, 256, 0, stream>>>(flat, rw1_w, rw1_b, yrw1, NG, 64, 128,
                                        stm3, sti3, bnpb_g, bnpb_b, 1);
    k_cs_part<<<128, 256, 0, stream>>>(yrw1, NG, 128, stm4, sti4);
    k_cs_fin<<<1, 128, 0, stream>>>(stm4, sti4, NG);
    k_gemm<<<NG / 32, 256, 0, stream>>>(yrw1, rw2_w, rw2_b, yrw2, NG, 128, 64,
                                        stm4, sti4, rw1_g, rw1_be, 1);
    k_cs_part<<<128, 256, 0, stream>>>(yrw2, NG, 64, stm5, sti5);
    k_cs_fin<<<1, 64, 0, stream>>>(stm5, sti5, NG);
    k_bn_apply<<<(NG * HH) / 256, 256, 0, stream>>>(yrw2, outb, NG * HH,
                                                    stm5, sti5, rw2_g, rw2_be);

    // ---- transformer ----
    k_gemm<<<NG / 32, 256, 0, stream>>>(outb, ain_w, ain_b, qkv, NG, 64, 192,
                                        nullptr, nullptr, nullptr, nullptr, 0);
    k_qkv_prep<<<dim3(GG / 64, BB * 2), 256, 0, stream>>>(qkv, Qb, Kb, Vt);
    k_attn_mfma<<<dim3(GG / 64, BB * 2), 256, 0, stream>>>(Qb, Kb, Vt, mask, ctxb);
    k_attn_out_ln<<<NG / 4, 256, 0, stream>>>(ctxb, outb, aout_w, aout_b, ln1_g, ln1_b, h1);
    k_gemm<<<NG / 32, 256, 0, stream>>>(h1, ff1_w, ff1_b, fft, NG, 64, FFD,
                                        nullptr, nullptr, nullptr, nullptr, 0);
    k_gemm<<<NG / 32, 256, 0, stream>>>(fft, ff2_w, ff2_b, ffo, NG, FFD, 64,
                                        nullptr, nullptr, nullptr, nullptr, 1);

    // ---- VAE ----
    k_vae_he<<<128, 256, 0, stream>>>(x, ve1_w, ve1_b, he);
    k_vae_mid<<<1, 128, 0, stream>>>(he, vmu_w, vmu_b, vlv_w, vlv_b, vd1_w, vd1_b,
                                     veps, hdc, outp + NG);

    // ---- final ----
    k_final<<<NG / 4, 256, 0, stream>>>(h1, ffo, ln2_g, ln2_b, indv_w, indv_b,
                                        hdc, vd2_w, vd2_b, x, outp);
}

// Round 3
// 697.584 us; speedup vs baseline: 1.6275x; 1.1611x over previous
//
#include <hip/hip_runtime.h>
#include <math.h>

#define GG 4096
#define PP 4096
#define HH 64
#define BB 4
#define E1N 81920
#define E2N 81920
#define FFD 512
#define BNEPS 1e-5f

typedef unsigned short ushort_t;
typedef unsigned int uint_t;
using sh8 = __attribute__((ext_vector_type(8))) short;
using f4  = __attribute__((ext_vector_type(4))) float;

// ---------------- workspace layout (float offsets) ----------------
#define OF_STATS   0          // 6 slots x 256 (raw sum[128] + sumsq[128])
#define OF_DEGCO   2048       // 4096 (contiguous with DEGGO for fused rsqrt)
#define OF_DEGGO   6144       // 4096
#define OF_PSLOT   10240      // 8 x 64
#define OF_ETOT    10752      // 4 x 64
#define OF_HDC     11008      // 4 x 32
#define OF_HE      11136      // 4 x 32
#define OF_AGGCO   12288      // 4096 x 64
#define OF_BASEIN  274432     // 4096 x 64
#define OF_Y1      536576     // 4096 x 64
#define OF_Y2      798720     // 4096 x 64
#define OF_FLAT    1060864    // 16384 x 64
#define OF_RW1     2109440    // 16384 x 128
#define OF_RW2     4206592    // 16384 x 64
#define OF_OUT     5255168    // 16384 x 64   (freed: attn partial split 3)
#define OF_QKV     6303744    // 16384 x 192  (after prep: attn partials 0..2)
#define OF_CTX     9449472    // 16384 x 64
#define OF_H1      10498048   // 16384 x 64
#define OF_FFT     OF_FLAT    // 16384 x 512 (aliases FLAT..QKV; all dead by then)
#define OF_FFO     OF_CTX     // 16384 x 64  (aliases CTX, dead by then)
// bf16 attention buffers (alias dead fp32 regions)
#define OF_QB      OF_AGGCO   // 8*4096*32 ushort = 524288 floats
#define OF_KB      (OF_AGGCO + 524288)
#define OF_VT      OF_FLAT    // 8*32*4096 ushort = 524288 floats
// attention k-split partials (dead regions at attention time)
#define OF_OPA     OF_QKV     // splits 0..2: 3 x 8*4096*32 fp32 = 3145728 (exact fit)
#define OF_OPB     OF_OUT     // split 3: 1048576
#define OF_MP      OF_RW1     // 4*8*4096 = 131072
#define OF_LP      (OF_RW1 + 131072)

__device__ inline ushort_t f2b(float f) {
    uint_t u = __builtin_bit_cast(uint_t, f);
    u += 0x7FFFu + ((u >> 16) & 1u);
    return (ushort_t)(u >> 16);
}

__device__ inline void gld16(const void* gptr, void* lptr) {
    __builtin_amdgcn_global_load_lds(
        (const __attribute__((address_space(1))) uint_t*)gptr,
        (__attribute__((address_space(3))) uint_t*)lptr, 16, 0, 0);
}

// ---------------- init: zero stats, deg arrays = 1 ----------------
__global__ void k_init(float* ws) {
    int i = blockIdx.x * 256 + threadIdx.x;   // 32 blocks -> 8192
    if (i < 2048) ws[OF_STATS + i] = 0.f;
    ws[OF_DEGCO + i] = 1.0f;                  // covers DEGCO+DEGGO (contiguous 8192)
}

__global__ void k_edge_deg(const int* __restrict__ ei, const float* __restrict__ w,
                           float* deg, int E) {
    int e = blockIdx.x * 256 + threadIdx.x;
    if (e < E) atomicAdd(&deg[ei[E + e]], w[e]);
}

__global__ void k_rsqrt_ip(float* p, int n) {
    int i = blockIdx.x * 256 + threadIdx.x;
    if (i < n) p[i] = rsqrtf(p[i]);
}

__global__ void k_agg_init(const float* __restrict__ x, const float* __restrict__ dinv,
                           float* agg, int n) {
    int i = blockIdx.x * 256 + threadIdx.x;
    if (i < n * HH) {
        int node = i >> 6;
        float di = dinv[node];
        agg[i] = x[i] * di * di;
    }
}

__global__ void k_edge_agg(const int* __restrict__ ei, const float* __restrict__ w,
                           const float* __restrict__ dinv, const float* __restrict__ x,
                           float* agg, int E) {
    int gid = blockIdx.x * 256 + threadIdx.x;
    int e = gid >> 6, h = gid & 63;
    if (e < E) {
        int src = ei[e], dst = ei[E + e];
        float norm = dinv[dst] * w[e] * dinv[src];
        atomicAdd(&agg[dst * HH + h], norm * x[src * HH + h]);
    }
}

// ---- coalesced column partial stats (finalize folded into consumers) ----
__global__ void k_cs_part(const float* __restrict__ X, int N, int C,
                          float* sum, float* sumsq) {
    int t = threadIdx.x;
    int col = t & (C - 1);
    int ro = t / C;
    int stride = 256 / C;
    int rows = N >> 7;
    int r0 = blockIdx.x * rows;
    float s = 0.f, q = 0.f;
    for (int r = r0 + ro; r < r0 + rows; r += stride) {
        float v = X[r * C + col];
        s += v; q += v * v;
    }
    __shared__ float ls[256], lq[256];
    ls[t] = s; lq[t] = q;
    __syncthreads();
    if (t < C) {
        for (int j = t + C; j < 256; j += C) { s += ls[j]; q += lq[j]; }
        atomicAdd(&sum[t], s);
        atomicAdd(&sumsq[t], q);
    }
}

// base_in = relu(bn(gene_emb)) + 0.2*(agg @ Wco^T + bco)   (raw stats)
__global__ void k_base_combine(const float* __restrict__ gene_emb, const float* __restrict__ agg,
                               const float* __restrict__ W, const float* __restrict__ bias,
                               const float* __restrict__ bsum, const float* __restrict__ bsq,
                               const float* __restrict__ bg, const float* __restrict__ bb,
                               float* out) {
    __shared__ float Wt[64][65];
    __shared__ float a[4][64];
    int t = threadIdx.x;
    for (int i = t; i < 4096; i += 256) Wt[i & 63][i >> 6] = W[i];
    int rr = t >> 6, h = t & 63;
    int g = blockIdx.x * 4 + rr;
    a[rr][h] = agg[g * 64 + h];
    __syncthreads();
    float y = bias[h];
    const float* ar = a[rr];
    #pragma unroll 8
    for (int k = 0; k < 64; k++) y += ar[k] * Wt[k][h];
    const float invN = 1.0f / (float)GG;
    float m = bsum[h] * invN;
    float is_ = rsqrtf(bsq[h] * invN - m * m + BNEPS);
    float v = gene_emb[g * 64 + h];
    v = (v - m) * is_ * bg[h] + bb[h];
    v = fmaxf(v, 0.f);
    out[g * 64 + h] = v + 0.2f * y;
}

// register-tiled fp32 GEMM: Y[N,Cout] = f(X[N,Cin]) @ W[Cout,Cin]^T + bias
// 64x64 block tile, 4x4 per-thread tile, float2 LDS reads (stride 66 -> 8B aligned)
__launch_bounds__(256)
__global__ void k_gemm64(const float* __restrict__ X, const float* __restrict__ W,
                         const float* __restrict__ bias, float* __restrict__ Y,
                         int Cin, int Cout,
                         const float* __restrict__ bnsum, const float* __restrict__ bnsq,
                         const float* __restrict__ bng, const float* __restrict__ bnb,
                         float invN, int relu_in) {
    __shared__ float Xs[64][66];
    __shared__ float Ws[64][66];
    __shared__ float bsc[64], bsh[64];
    const int t = threadIdx.x;
    const int row0 = blockIdx.x * 64, cb = blockIdx.y * 64;
    const int tx = t & 15, ty = t >> 4;
    const int c0 = tx * 4, r0 = ty * 4;
    float acc[4][4];
    #pragma unroll
    for (int j = 0; j < 4; j++)
        #pragma unroll
        for (int i = 0; i < 4; i++) acc[j][i] = 0.f;

    for (int k0 = 0; k0 < Cin; k0 += 64) {
        __syncthreads();
        if (t < 64) {
            float sc = 1.f, sh = 0.f;
            if (bnsum) {
                int c = k0 + t;
                float m = bnsum[c] * invN;
                float is_ = rsqrtf(bnsq[c] * invN - m * m + BNEPS);
                sc = is_ * bng[c]; sh = bnb[c] - m * sc;
            }
            bsc[t] = sc; bsh[t] = sh;
        }
        __syncthreads();
        for (int i = t; i < 1024; i += 256) {
            int r = i >> 4, kq = (i & 15) * 4;
            float4 v = *(const float4*)&X[(size_t)(row0 + r) * Cin + k0 + kq];
            float e0 = v.x * bsc[kq] + bsh[kq];
            float e1 = v.y * bsc[kq + 1] + bsh[kq + 1];
            float e2 = v.z * bsc[kq + 2] + bsh[kq + 2];
            float e3 = v.w * bsc[kq + 3] + bsh[kq + 3];
            if (relu_in) {
                e0 = fmaxf(e0, 0.f); e1 = fmaxf(e1, 0.f);
                e2 = fmaxf(e2, 0.f); e3 = fmaxf(e3, 0.f);
            }
            Xs[r][kq] = e0; Xs[r][kq + 1] = e1; Xs[r][kq + 2] = e2; Xs[r][kq + 3] = e3;
            float4 wv = *(const float4*)&W[(size_t)(cb + r) * Cin + k0 + kq];
            Ws[r][kq] = wv.x; Ws[r][kq + 1] = wv.y; Ws[r][kq + 2] = wv.z; Ws[r][kq + 3] = wv.w;
        }
        __syncthreads();
        #pragma unroll 4
        for (int k = 0; k < 64; k += 2) {
            float2 a[4], b[4];
            #pragma unroll
            for (int j = 0; j < 4; j++) a[j] = *(const float2*)&Xs[r0 + j][k];
            #pragma unroll
            for (int i = 0; i < 4; i++) b[i] = *(const float2*)&Ws[c0 + i][k];
            #pragma unroll
            for (int j = 0; j < 4; j++)
                #pragma unroll
                for (int i = 0; i < 4; i++)
                    acc[j][i] += a[j].x * b[i].x + a[j].y * b[i].y;
        }
    }
    float4 bi = *(const float4*)&bias[cb + c0];
    #pragma unroll
    for (int j = 0; j < 4; j++) {
        float4 o;
        o.x = acc[j][0] + bi.x; o.y = acc[j][1] + bi.y;
        o.z = acc[j][2] + bi.z; o.w = acc[j][3] + bi.w;
        *(float4*)&Y[(size_t)(row0 + r0 + j) * Cout + cb + c0] = o;
    }
}

// flat_pre[b,g,h] = bn(y2)[g,h] + etot[b,h]   (raw stats over G rows)
__global__ void k_flatpre(const float* __restrict__ y2, const float* __restrict__ etot,
                          const float* __restrict__ bsum, const float* __restrict__ bsq,
                          const float* __restrict__ g2, const float* __restrict__ b2,
                          float* out) {
    int i = blockIdx.x * 256 + threadIdx.x;
    int h = i & 63;
    int b = i >> 18;
    int gh = i & (GG * HH - 1);
    const float invN = 1.0f / (float)GG;
    float m = bsum[h] * invN;
    float is_ = rsqrtf(bsq[h] * invN - m * m + BNEPS);
    float v = y2[gh];
    v = (v - m) * is_ * g2[h] + b2[h];
    out[i] = v + etot[b * 64 + h];
}

__global__ void k_pert_slots(const int* __restrict__ pidx, const float* __restrict__ tbl,
                             const float* __restrict__ dinv, float* pslot) {
    int i = threadIdx.x;
    int s = i >> 6, h = i & 63;
    int n = pidx[s];
    float di = dinv[n];
    pslot[i] = tbl[n * 64 + h] * di * di;
}

__global__ void k_pert_edges(const int* __restrict__ pidx, const int* __restrict__ ei,
                             const float* __restrict__ w, const float* __restrict__ dinv,
                             const float* __restrict__ tbl, float* pslot) {
    int e = blockIdx.x * 256 + threadIdx.x;
    if (e >= E2N) return;
    int dst = ei[E2N + e];
    int src = ei[e];
    for (int s = 0; s < 8; s++) {
        if (pidx[s] == dst) {
            float norm = dinv[dst] * w[e] * dinv[src];
            for (int h = 0; h < 64; h++)
                atomicAdd(&pslot[s * 64 + h], norm * tbl[src * 64 + h]);
        }
    }
}

__global__ void k_pert_mlp(const float* __restrict__ pslot,
                           const float* __restrict__ gw, const float* __restrict__ gb,
                           const float* __restrict__ w1, const float* __restrict__ b1,
                           const float* __restrict__ g1, const float* __restrict__ be1,
                           const float* __restrict__ w2, const float* __restrict__ b2,
                           const float* __restrict__ g2, const float* __restrict__ be2,
                           float* etot) {
    __shared__ float pge[8][64], psum[4][64], y[4][64], mh[64], ih[64];
    int t = threadIdx.x;
    for (int j = t; j < 512; j += 256) {
        int s = j >> 6, h = j & 63;
        float acc = gb[h];
        for (int k = 0; k < 64; k++) acc += pslot[s * 64 + k] * gw[h * 64 + k];
        pge[s][h] = acc;
    }
    __syncthreads();
    { int b = t >> 6, h = t & 63; psum[b][h] = pge[2 * b][h] + pge[2 * b + 1][h]; }
    __syncthreads();
    { int b = t >> 6, h = t & 63;
      float acc = b1[h];
      for (int k = 0; k < 64; k++) acc += psum[b][k] * w1[h * 64 + k];
      y[b][h] = acc; }
    __syncthreads();
    if (t < 64) {
        float s = 0.f, sq = 0.f;
        for (int b = 0; b < 4; b++) { float v = y[b][t]; s += v; sq += v * v; }
        float m = s * 0.25f;
        mh[t] = m; ih[t] = rsqrtf(sq * 0.25f - m * m + BNEPS);
    }
    __syncthreads();
    { int b = t >> 6, h = t & 63;
      float v = (y[b][h] - mh[h]) * ih[h] * g1[h] + be1[h];
      psum[b][h] = fmaxf(v, 0.f); }
    __syncthreads();
    { int b = t >> 6, h = t & 63;
      float acc = b2[h];
      for (int k = 0; k < 64; k++) acc += psum[b][k] * w2[h * 64 + k];
      y[b][h] = acc; }
    __syncthreads();
    if (t < 64) {
        float s = 0.f, sq = 0.f;
        for (int b = 0; b < 4; b++) { float v = y[b][t]; s += v; sq += v * v; }
        float m = s * 0.25f;
        mh[t] = m; ih[t] = rsqrtf(sq * 0.25f - m * m + BNEPS);
    }
    __syncthreads();
    { int b = t >> 6, h = t & 63;
      etot[b * 64 + h] = (y[b][h] - mh[h]) * ih[h] * g2[h] + be2[h]; }
}

// ---- qkv prep: fp32 [B*G][192] -> bf16 Qb/Kb [bh][4096][32], Vt [bh][32][4096]
__global__ void k_qkv_prep(const float* __restrict__ qkv, ushort_t* __restrict__ Qb,
                           ushort_t* __restrict__ Kb, ushort_t* __restrict__ Vtg) {
    const int bh = blockIdx.y, b = bh >> 1, h = bh & 1;
    const int g0 = blockIdx.x * 64;
    const int t = threadIdx.x;
    const int row = t >> 2, d0 = (t & 3) * 8;
    __shared__ ushort_t Lv[64][33];
    size_t base = ((size_t)(b * GG + g0 + row)) * 192 + h * 32 + d0;
    union { ushort_t u[8]; uint4 v; } pk;
    {
        float4 a = *(const float4*)&qkv[base];
        float4 c = *(const float4*)&qkv[base + 4];
        pk.u[0] = f2b(a.x); pk.u[1] = f2b(a.y); pk.u[2] = f2b(a.z); pk.u[3] = f2b(a.w);
        pk.u[4] = f2b(c.x); pk.u[5] = f2b(c.y); pk.u[6] = f2b(c.z); pk.u[7] = f2b(c.w);
        *(uint4*)&Qb[((size_t)bh * GG + g0 + row) * 32 + d0] = pk.v;
    }
    {
        float4 a = *(const float4*)&qkv[base + 64];
        float4 c = *(const float4*)&qkv[base + 68];
        pk.u[0] = f2b(a.x); pk.u[1] = f2b(a.y); pk.u[2] = f2b(a.z); pk.u[3] = f2b(a.w);
        pk.u[4] = f2b(c.x); pk.u[5] = f2b(c.y); pk.u[6] = f2b(c.z); pk.u[7] = f2b(c.w);
        *(uint4*)&Kb[((size_t)bh * GG + g0 + row) * 32 + d0] = pk.v;
    }
    {
        float4 a = *(const float4*)&qkv[base + 128];
        float4 c = *(const float4*)&qkv[base + 132];
        Lv[row][d0 + 0] = f2b(a.x); Lv[row][d0 + 1] = f2b(a.y);
        Lv[row][d0 + 2] = f2b(a.z); Lv[row][d0 + 3] = f2b(a.w);
        Lv[row][d0 + 4] = f2b(c.x); Lv[row][d0 + 5] = f2b(c.y);
        Lv[row][d0 + 6] = f2b(c.z); Lv[row][d0 + 7] = f2b(c.w);
    }
    __syncthreads();
    {
        int d = t >> 3, koff = (t & 7) * 8;
        #pragma unroll
        for (int j = 0; j < 8; j++) pk.u[j] = Lv[koff + j][d];
        *(uint4*)&Vtg[((size_t)bh * 32 + d) * GG + g0 + koff] = pk.v;
    }
}

// ---- MFMA flash attention, k-split ----
// grid (G/64, 8 bh, 4 splits), block 256 = 4 waves; wave w owns q rows [q0+16w, +16)
__launch_bounds__(256)
__global__ void k_attn_mfma(const ushort_t* __restrict__ Qb, const ushort_t* __restrict__ Kb,
                            const ushort_t* __restrict__ Vtg, const float* __restrict__ mask,
                            float* __restrict__ opA, float* __restrict__ opB,
                            float* __restrict__ Mp, float* __restrict__ Lp) {
    __shared__ ushort_t Ql[2048];
    __shared__ ushort_t Kl[2048];
    __shared__ ushort_t Vl[2048];
    __shared__ ushort_t Ps[4][1024];

    const int bh = blockIdx.y;
    const int split = blockIdx.z;
    const int q0 = blockIdx.x * 64;
    const int kstart = split * (GG / 4), kend = kstart + (GG / 4);
    const int t = threadIdx.x;
    const int lane = t & 63, w = t >> 6;
    const int l15 = lane & 15, quad = lane >> 4;
    const float scale = 0.17677669529663687f;

    {
        const ushort_t* g = Qb + ((size_t)bh * GG + q0 + (t >> 6) * 16 + (t & 15)) * 32
                               + ((t >> 4) & 3) * 8;
        gld16(g, &Ql[t * 8]);
    }

    f4 O0 = {0.f, 0.f, 0.f, 0.f}, O1 = {0.f, 0.f, 0.f, 0.f};
    float mr[4], lr[4];
    #pragma unroll
    for (int r = 0; r < 4; r++) { mr[r] = -1e30f; lr[r] = 0.f; }
    sh8 qf;

    for (int k0 = kstart; k0 < kend; k0 += 64) {
        __syncthreads();
        {
            const ushort_t* gk = Kb + ((size_t)bh * GG + k0 + (t >> 6) * 16 + (t & 15)) * 32
                                    + ((t >> 4) & 3) * 8;
            gld16(gk, &Kl[t * 8]);
            int kstep = t >> 7, nt = (t >> 6) & 1;
            const ushort_t* gv = Vtg + ((size_t)bh * 32 + nt * 16 + (t & 15)) * GG
                                     + k0 + kstep * 32 + ((t >> 4) & 3) * 8;
            gld16(gv, &Vl[t * 8]);
        }
        __syncthreads();
        if (k0 == kstart) qf = *(const sh8*)&Ql[(w * 64 + lane) * 8];

        f4 s[4];
        #pragma unroll
        for (int i2 = 0; i2 < 4; i2++) {
            sh8 kf = *(const sh8*)&Kl[(i2 * 64 + lane) * 8];
            f4 z = {0.f, 0.f, 0.f, 0.f};
            s[i2] = __builtin_amdgcn_mfma_f32_16x16x32_bf16(qf, kf, z, 0, 0, 0);
        }
        const float* mbase = mask + (size_t)(q0 + w * 16 + quad * 4) * GG + k0 + l15;
        float mx[4];
        #pragma unroll
        for (int r = 0; r < 4; r++) {
            float pm = -1e30f;
            #pragma unroll
            for (int i2 = 0; i2 < 4; i2++) {
                float sc = s[i2][r] * scale + mbase[(size_t)r * GG + i2 * 16];
                s[i2][r] = sc;
                pm = fmaxf(pm, sc);
            }
            mx[r] = pm;
        }
        #pragma unroll
        for (int off = 1; off < 16; off <<= 1) {
            #pragma unroll
            for (int r = 0; r < 4; r++) mx[r] = fmaxf(mx[r], __shfl_xor(mx[r], off, 64));
        }
        float al[4];
        #pragma unroll
        for (int r = 0; r < 4; r++) {
            float nm = fmaxf(mr[r], mx[r]);
            al[r] = __expf(mr[r] - nm);
            mr[r] = nm;
        }
        float rs[4];
        #pragma unroll
        for (int r = 0; r < 4; r++) {
            float ss = 0.f;
            #pragma unroll
            for (int i2 = 0; i2 < 4; i2++) {
                float p = __expf(s[i2][r] - mr[r]);
                s[i2][r] = p;
                ss += p;
            }
            rs[r] = ss;
        }
        #pragma unroll
        for (int off = 1; off < 16; off <<= 1) {
            #pragma unroll
            for (int r = 0; r < 4; r++) rs[r] += __shfl_xor(rs[r], off, 64);
        }
        #pragma unroll
        for (int r = 0; r < 4; r++) {
            lr[r] = lr[r] * al[r] + rs[r];
            O0[r] *= al[r];
            O1[r] *= al[r];
        }
        #pragma unroll
        for (int i2 = 0; i2 < 4; i2++) {
            int bofs = (i2 >> 1) * 512 + (((i2 & 1) * 2 + (l15 >> 3)) * 16) * 8 + (l15 & 7);
            #pragma unroll
            for (int r = 0; r < 4; r++)
                Ps[w][bofs + (quad * 4 + r) * 8] = f2b(s[i2][r]);
        }
        #pragma unroll
        for (int kstep = 0; kstep < 2; kstep++) {
            sh8 pf = *(const sh8*)&Ps[w][(kstep * 64 + lane) * 8];
            sh8 vf0 = *(const sh8*)&Vl[((kstep * 2 + 0) * 64 + lane) * 8];
            sh8 vf1 = *(const sh8*)&Vl[((kstep * 2 + 1) * 64 + lane) * 8];
            O0 = __builtin_amdgcn_mfma_f32_16x16x32_bf16(pf, vf0, O0, 0, 0, 0);
            O1 = __builtin_amdgcn_mfma_f32_16x16x32_bf16(pf, vf1, O1, 0, 0, 0);
        }
    }
    // epilogue: unnormalized partials + (m, l)
    float* op = (split < 3) ? (opA + (size_t)split * (8 * GG * 32)) : opB;
    #pragma unroll
    for (int r = 0; r < 4; r++) {
        int q = q0 + w * 16 + quad * 4 + r;
        size_t o = ((size_t)bh * GG + q) * 32 + l15;
        op[o] = O0[r];
        op[o + 16] = O1[r];
    }
    if (l15 == 0) {
        #pragma unroll
        for (int r = 0; r < 4; r++) {
            int q = q0 + w * 16 + quad * 4 + r;
            int mi = (split * 8 + bh) * GG + q;
            Mp[mi] = mr[r];
            Lp[mi] = lr[r];
        }
    }
}

// combine 4 k-split partials -> ctx
__global__ void k_attn_comb(const float* __restrict__ opA, const float* __restrict__ opB,
                            const float* __restrict__ Mp, const float* __restrict__ Lp,
                            float* __restrict__ ctx) {
    int i = blockIdx.x * 256 + threadIdx.x;        // < 8*4096*32
    int d = i & 31;
    int q = (i >> 5) & (GG - 1);
    int bh = i >> 17;
    int mlq = bh * GG + q;
    float m0 = Mp[mlq], m1 = Mp[32768 + mlq], m2 = Mp[65536 + mlq], m3 = Mp[98304 + mlq];
    float mm = fmaxf(fmaxf(m0, m1), fmaxf(m2, m3));
    float e0 = __expf(m0 - mm), e1 = __expf(m1 - mm);
    float e2 = __expf(m2 - mm), e3 = __expf(m3 - mm);
    float denom = e0 * Lp[mlq] + e1 * Lp[32768 + mlq] + e2 * Lp[65536 + mlq] + e3 * Lp[98304 + mlq];
    float acc = e0 * opA[i] + e1 * opA[1048576 + i] + e2 * opA[2097152 + i] + e3 * opB[i];
    int b = bh >> 1, h = bh & 1;
    ctx[((size_t)(b * GG + q)) * 64 + h * 32 + d] = acc / denom;
}

// att = ctx @ Wout^T + b ; h1 = LN(bn(yrw2) + att)   (BN finalize inline)
__global__ void k_attn_out_ln(const float* __restrict__ ctxb, const float* __restrict__ yrw2,
                              const float* __restrict__ W, const float* __restrict__ bias,
                              const float* __restrict__ bsum, const float* __restrict__ bsq,
                              const float* __restrict__ bg, const float* __restrict__ bb,
                              const float* __restrict__ lg, const float* __restrict__ lb,
                              float* __restrict__ h1) {
    __shared__ float Wt[64][65];
    __shared__ float Cs[4][64];
    int t = threadIdx.x;
    for (int i = t; i < 4096; i += 256) Wt[i & 63][i >> 6] = W[i];
    int rr = t >> 6, lane = t & 63;
    int row = blockIdx.x * 4 + rr;
    Cs[rr][lane] = ctxb[row * 64 + lane];
    __syncthreads();
    float acc = bias[lane];
    const float* cr = Cs[rr];
    #pragma unroll 8
    for (int k = 0; k < 64; k++) acc += cr[k] * Wt[k][lane];
    const float invN = 1.0f / (float)(BB * GG);
    float m = bsum[lane] * invN;
    float is_ = rsqrtf(bsq[lane] * invN - m * m + BNEPS);
    float ov = (yrw2[row * 64 + lane] - m) * is_ * bg[lane] + bb[lane];
    float v = ov + acc;
    float s = v;
    for (int o = 32; o > 0; o >>= 1) s += __shfl_xor(s, o, 64);
    float mean = s * (1.f / 64.f);
    float d = v - mean;
    float sq = d * d;
    for (int o = 32; o > 0; o >>= 1) sq += __shfl_xor(sq, o, 64);
    float inv = rsqrtf(sq * (1.f / 64.f) + BNEPS);
    h1[row * 64 + lane] = d * inv * lg[lane] + lb[lane];
}

__global__ void k_final(const float* __restrict__ h1, const float* __restrict__ ffo,
                        const float* __restrict__ lg, const float* __restrict__ lb,
                        const float* __restrict__ indvw, const float* __restrict__ indvb,
                        const float* __restrict__ hdc, const float* __restrict__ d2w,
                        const float* __restrict__ d2b, const float* __restrict__ x,
                        float* __restrict__ outp) {
    int t = threadIdx.x;
    int rr = t >> 6, lane = t & 63;
    int row = blockIdx.x * 4 + rr;
    int b = row >> 12, g = row & 4095;
    float v = h1[row * 64 + lane] + ffo[row * 64 + lane];
    float s = v;
    for (int o = 32; o > 0; o >>= 1) s += __shfl_xor(s, o, 64);
    float mean = s * (1.f / 64.f);
    float d = v - mean;
    float sq = d * d;
    for (int o = 32; o > 0; o >>= 1) sq += __shfl_xor(sq, o, 64);
    float inv = rsqrtf(sq * (1.f / 64.f) + BNEPS);
    float enc = d * inv * lg[lane] + lb[lane];
    float p = enc * indvw[g * 64 + lane];
    for (int o = 32; o > 0; o >>= 1) p += __shfl_xor(p, o, 64);
    float rc = 0.f;
    if (lane < 32) rc = hdc[b * 32 + lane] * d2w[g * 32 + lane];
    for (int o = 16; o > 0; o >>= 1) rc += __shfl_xor(rc, o, 64);
    if (lane == 0) {
        float recon = rc + d2b[g];
        if (x[row] == 0.f) recon = 0.f;
        outp[row] = p + indvb[g] + recon;
    }
}

__global__ void k_vae_he(const float* __restrict__ x, const float* __restrict__ W,
                         const float* __restrict__ bias, float* he) {
    int b = blockIdx.x >> 5, i = blockIdx.x & 31;
    float s = 0.f;
    for (int g = threadIdx.x; g < 4096; g += 256) s += x[b * 4096 + g] * W[i * 4096 + g];
    __shared__ float ls[256];
    ls[threadIdx.x] = s;
    __syncthreads();
    for (int o = 128; o > 0; o >>= 1) {
        if (threadIdx.x < o) ls[threadIdx.x] += ls[threadIdx.x + o];
        __syncthreads();
    }
    if (threadIdx.x == 0) he[b * 32 + i] = fmaxf(ls[0] + bias[i], 0.f);
}

__global__ void k_vae_mid(const float* __restrict__ he,
                          const float* __restrict__ muw, const float* __restrict__ mub,
                          const float* __restrict__ lvw, const float* __restrict__ lvb,
                          const float* __restrict__ d1w, const float* __restrict__ d1b,
                          const float* __restrict__ eps, float* hdc, float* klout) {
    __shared__ float zs[64];
    int t = threadIdx.x;
    if (t < 64) {
        int b = t >> 4, l = t & 15;
        float mu = mub[l], lv = lvb[l];
        for (int i = 0; i < 32; i++) {
            float hv = he[b * 32 + i];
            mu += hv * muw[l * 32 + i];
            lv += hv * lvw[l * 32 + i];
        }
        zs[t] = mu + eps[t] * expf(0.5f * lv);
        float kterm = 1.f + lv - mu * mu - expf(lv);
        for (int o = 32; o > 0; o >>= 1) kterm += __shfl_xor(kterm, o, 64);
        if (t == 0) klout[0] = -0.5f * kterm * 0.25f;
    }
    __syncthreads();
    {
        int b = t >> 5, i = t & 31;
        float a = d1b[i];
        for (int l = 0; l < 16; l++) a += zs[b * 16 + l] * d1w[i * 16 + l];
        hdc[t] = fmaxf(a, 0.f);
    }
}

extern "C" void kernel_launch(void* const* d_in, const int* in_sizes, int n_in,
                              void* d_out, int out_size, void* d_ws, size_t ws_size,
                              hipStream_t stream) {
    const float* x        = (const float*)d_in[0];
    const int*   pert_idx = (const int*)  d_in[1];
    const float* mask     = (const float*)d_in[2];
    const int*   ei_co    = (const int*)  d_in[3];
    const float* w_co     = (const float*)d_in[4];
    const int*   ei_go    = (const int*)  d_in[5];
    const float* w_go     = (const float*)d_in[6];
    const float* gene_emb = (const float*)d_in[7];
    const float* emb_pos  = (const float*)d_in[8];
    const float* pert_tbl = (const float*)d_in[9];
    const float* sg_co_w  = (const float*)d_in[10];
    const float* sg_co_b  = (const float*)d_in[11];
    const float* sg_go_w  = (const float*)d_in[12];
    const float* sg_go_b  = (const float*)d_in[13];
    const float* bn_emb_g = (const float*)d_in[14];
    const float* bn_emb_b = (const float*)d_in[15];
    const float* etv1_w   = (const float*)d_in[16];
    const float* etv1_b   = (const float*)d_in[17];
    const float* etv1_g   = (const float*)d_in[18];
    const float* etv1_be  = (const float*)d_in[19];
    const float* etv2_w   = (const float*)d_in[20];
    const float* etv2_b   = (const float*)d_in[21];
    const float* etv2_g   = (const float*)d_in[22];
    const float* etv2_be  = (const float*)d_in[23];
    const float* pf1_w    = (const float*)d_in[24];
    const float* pf1_b    = (const float*)d_in[25];
    const float* pf1_g    = (const float*)d_in[26];
    const float* pf1_be   = (const float*)d_in[27];
    const float* pf2_w    = (const float*)d_in[28];
    const float* pf2_b    = (const float*)d_in[29];
    const float* pf2_g    = (const float*)d_in[30];
    const float* pf2_be   = (const float*)d_in[31];
    const float* rw1_w    = (const float*)d_in[32];
    const float* rw1_b    = (const float*)d_in[33];
    const float* rw1_g    = (const float*)d_in[34];
    const float* rw1_be   = (const float*)d_in[35];
    const float* rw2_w    = (const float*)d_in[36];
    const float* rw2_b    = (const float*)d_in[37];
    const float* rw2_g    = (const float*)d_in[38];
    const float* rw2_be   = (const float*)d_in[39];
    const float* bnpb_g   = (const float*)d_in[40];
    const float* bnpb_b   = (const float*)d_in[41];
    const float* ain_w    = (const float*)d_in[42];
    const float* ain_b    = (const float*)d_in[43];
    const float* aout_w   = (const float*)d_in[44];
    const float* aout_b   = (const float*)d_in[45];
    const float* ln1_g    = (const float*)d_in[46];
    const float* ln1_b    = (const float*)d_in[47];
    const float* ff1_w    = (const float*)d_in[48];
    const float* ff1_b    = (const float*)d_in[49];
    const float* ff2_w    = (const float*)d_in[50];
    const float* ff2_b    = (const float*)d_in[51];
    const float* ln2_g    = (const float*)d_in[52];
    const float* ln2_b    = (const float*)d_in[53];
    const float* indv_w   = (const float*)d_in[54];
    const float* indv_b   = (const float*)d_in[55];
    const float* ve1_w    = (const float*)d_in[56];
    const float* ve1_b    = (const float*)d_in[57];
    const float* vmu_w    = (const float*)d_in[58];
    const float* vmu_b    = (const float*)d_in[59];
    const float* vlv_w    = (const float*)d_in[60];
    const float* vlv_b    = (const float*)d_in[61];
    const float* vd1_w    = (const float*)d_in[62];
    const float* vd1_b    = (const float*)d_in[63];
    const float* vd2_w    = (const float*)d_in[64];
    const float* vd2_b    = (const float*)d_in[65];
    const float* veps     = (const float*)d_in[66];

    float* ws   = (float*)d_ws;
    float* outp = (float*)d_out;

    float* stm0 = ws + OF_STATS + 0 * 256; float* sti0 = stm0 + 128;
    float* stm1 = ws + OF_STATS + 1 * 256; float* sti1 = stm1 + 128;
    float* stm2 = ws + OF_STATS + 2 * 256; float* sti2 = stm2 + 128;
    float* stm3 = ws + OF_STATS + 3 * 256; float* sti3 = stm3 + 128;
    float* stm4 = ws + OF_STATS + 4 * 256; float* sti4 = stm4 + 128;
    float* stm5 = ws + OF_STATS + 5 * 256; float* sti5 = stm5 + 128;

    float* degco  = ws + OF_DEGCO;
    float* deggo  = ws + OF_DEGGO;
    float* pslot  = ws + OF_PSLOT;
    float* etot   = ws + OF_ETOT;
    float* hdc    = ws + OF_HDC;
    float* he     = ws + OF_HE;
    float* aggco  = ws + OF_AGGCO;
    float* basein = ws + OF_BASEIN;
    float* y1     = ws + OF_Y1;
    float* y2     = ws + OF_Y2;
    float* flat   = ws + OF_FLAT;
    float* yrw1   = ws + OF_RW1;
    float* yrw2   = ws + OF_RW2;
    float* qkv    = ws + OF_QKV;
    float* ctxb   = ws + OF_CTX;
    float* h1     = ws + OF_H1;
    float* fft    = ws + OF_FFT;
    float* ffo    = ws + OF_FFO;
    float* opA    = ws + OF_OPA;
    float* opB    = ws + OF_OPB;
    float* Mp     = ws + OF_MP;
    float* Lp     = ws + OF_LP;
    ushort_t* Qb  = (ushort_t*)(ws + OF_QB);
    ushort_t* Kb  = (ushort_t*)(ws + OF_KB);
    ushort_t* Vt  = (ushort_t*)(ws + OF_VT);

    const int NG = BB * GG; // 16384
    const float iG = 1.0f / (float)GG, iNG = 1.0f / (float)NG;

    // ---- init + degrees for both graphs ----
    k_init<<<32, 256, 0, stream>>>(ws);
    k_edge_deg<<<(E1N + 255) / 256, 256, 0, stream>>>(ei_co, w_co, degco, E1N);
    k_edge_deg<<<(E2N + 255) / 256, 256, 0, stream>>>(ei_go, w_go, deggo, E2N);
    k_rsqrt_ip<<<32, 256, 0, stream>>>(degco, 8192);   // covers degco+deggo

    // ---- co-graph SGConv + gene base ----
    k_agg_init<<<(GG * HH) / 256, 256, 0, stream>>>(emb_pos, degco, aggco, GG);
    k_edge_agg<<<(E1N * 64) / 256, 256, 0, stream>>>(ei_co, w_co, degco, emb_pos, aggco, E1N);
    k_cs_part<<<128, 256, 0, stream>>>(gene_emb, GG, 64, stm0, sti0);
    k_base_combine<<<GG / 4, 256, 0, stream>>>(gene_emb, aggco, sg_co_w, sg_co_b,
                                               stm0, sti0, bn_emb_g, bn_emb_b, basein);
    // etv MLP
    k_gemm64<<<dim3(GG / 64, 1), 256, 0, stream>>>(basein, etv1_w, etv1_b, y1, 64, 64,
                                                   nullptr, nullptr, nullptr, nullptr, 0.f, 0);
    k_cs_part<<<128, 256, 0, stream>>>(y1, GG, 64, stm1, sti1);
    k_gemm64<<<dim3(GG / 64, 1), 256, 0, stream>>>(y1, etv2_w, etv2_b, y2, 64, 64,
                                                   stm1, sti1, etv1_g, etv1_be, iG, 1);
    k_cs_part<<<128, 256, 0, stream>>>(y2, GG, 64, stm2, sti2);

    // ---- go-graph SGConv (8 gathered rows) + pert MLP ----
    k_pert_slots<<<1, 512, 0, stream>>>(pert_idx, pert_tbl, deggo, pslot);
    k_pert_edges<<<(E2N + 255) / 256, 256, 0, stream>>>(pert_idx, ei_go, w_go, deggo,
                                                        pert_tbl, pslot);
    k_pert_mlp<<<1, 256, 0, stream>>>(pslot, sg_go_w, sg_go_b,
                                      pf1_w, pf1_b, pf1_g, pf1_be,
                                      pf2_w, pf2_b, pf2_g, pf2_be, etot);

    // ---- fuse, rw MLP ----
    k_flatpre<<<(NG * HH) / 256, 256, 0, stream>>>(y2, etot, stm2, sti2, etv2_g, etv2_be, flat);
    k_cs_part<<<128, 256, 0, stream>>>(flat, NG, 64, stm3, sti3);
    k_gemm64<<<dim3(NG / 64, 2), 256, 0, stream>>>(flat, rw1_w, rw1_b, yrw1, 64, 128,
                                                   stm3, sti3, bnpb_g, bnpb_b, iNG, 1);
    k_cs_part<<<128, 256, 0, stream>>>(yrw1, NG, 128, stm4, sti4);
    k_gemm64<<<dim3(NG / 64, 1), 256, 0, stream>>>(yrw1, rw2_w, rw2_b, yrw2, 128, 64,
                                                   stm4, sti4, rw1_g, rw1_be, iNG, 1);
    k_cs_part<<<128, 256, 0, stream>>>(yrw2, NG, 64, stm5, sti5);

    // ---- transformer ----
    k_gemm64<<<dim3(NG / 64, 3), 256, 0, stream>>>(yrw2, ain_w, ain_b, qkv, 64, 192,
                                                   stm5, sti5, rw2_g, rw2_be, iNG, 0);
    k_qkv_prep<<<dim3(GG / 64, BB * 2), 256, 0, stream>>>(qkv, Qb, Kb, Vt);
    k_attn_mfma<<<dim3(GG / 64, BB * 2, 4), 256, 0, stream>>>(Qb, Kb, Vt, mask,
                                                              opA, opB, Mp, Lp);
    k_attn_comb<<<4096, 256, 0, stream>>>(opA, opB, Mp, Lp, ctxb);
    k_attn_out_ln<<<NG / 4, 256, 0, stream>>>(ctxb, yrw2, aout_w, aout_b,
                                              stm5, sti5, rw2_g, rw2_be,
                                              ln1_g, ln1_b, h1);
    k_gemm64<<<dim3(NG / 64, FFD / 64), 256, 0, stream>>>(h1, ff1_w, ff1_b, fft, 64, FFD,
                                                          nullptr, nullptr, nullptr, nullptr, 0.f, 0);
    k_gemm64<<<dim3(NG / 64, 1), 256, 0, stream>>>(fft, ff2_w, ff2_b, ffo, FFD, 64,
                                                   nullptr, nullptr, nullptr, nullptr, 0.f, 1);

    // ---- VAE ----
    k_vae_he<<<128, 256, 0, stream>>>(x, ve1_w, ve1_b, he);
    k_vae_mid<<<1, 128, 0, stream>>>(he, vmu_w, vmu_b, vlv_w, vlv_b, vd1_w, vd1_b,
                                     veps, hdc, outp + NG);

    // ---- final ----
    k_final<<<NG / 4, 256, 0, stream>>>(h1, ffo, ln2_g, ln2_b, indv_w, indv_b,
                                        hdc, vd2_w, vd2_b, x, outp);
}